// Round 4
// baseline (277.470 us; speedup 1.0000x reference)
//
#include <hip/hip_runtime.h>
#include <hip/hip_bf16.h>

#define N0   3000
#define E0   48000
#define K1N  1500
#define K2N  750
#define HID  128
#define CAP  128
#define LD1  1536  // (A1 dense retired; offset kept for layout compat)
#define LD2  768   // padded leading dim for A2/Ac
#define BM   32    // row-tile for yw2
#define ATS  36    // transposed X-tile stride (BM+4, bank-spread)
#define RCAP 1536  // CSR row capacity (>= max possible nnz = K1N)
#define TKT  1024  // k_topk threads (16 waves on one CU)
#define NBC  188   // edge-count blocks in k_cntyw ((E0+255)/256)
#define NBY0 94    // yw2 L0 blocks ((N0+BM-1)/BM)
#define NBY1 47    // yw2 L1/up blocks ((K1N+BM-1)/BM)
#define NBY2 24    // yw2 L2 blocks ((K2N+BM-1)/BM)

__device__ __forceinline__ unsigned fkey(float f) {
  unsigned u = __float_as_uint(f);
  return (u & 0x80000000u) ? ~u : (u | 0x80000000u);
}
__device__ __forceinline__ float inv_fkey(unsigned u) {
  unsigned v = (u & 0x80000000u) ? (u & 0x7FFFFFFFu) : ~u;
  return __uint_as_float(v);
}

// ---------------- workspace layout (float units) ----------------
constexpr size_t F_A1    = 0;                          // retired (hole)
constexpr size_t F_SCR   = F_A1 + (size_t)K1N * LD1;   // Ac (int16) = K1N*LD2 shorts
constexpr size_t SCR_SZ  = 1155072;
constexpr size_t F_A2    = F_SCR + SCR_SZ;             // K2N*LD2
constexpr size_t F_YSC   = F_A2 + (size_t)K2N * LD2;   // N0*HID
constexpr size_t F_H0    = F_YSC + (size_t)N0 * HID;   // N0*HID
constexpr size_t F_H1    = F_H0 + (size_t)N0 * HID;    // K1N*HID
constexpr size_t F_H2    = F_H1 + (size_t)K1N * HID;   // K2N*HID
constexpr size_t F_U1    = F_H2 + (size_t)K2N * HID;   // (hole)
constexpr size_t F_U1B   = F_U1 + (size_t)K1N * HID;   // K1N*HID
constexpr size_t F_YF    = F_U1B + (size_t)K1N * HID;  // N0*3
constexpr size_t F_SCORE = F_YF + (size_t)N0 * 3;      // N0
constexpr size_t F_GATE1 = F_SCORE + N0;               // K1N
constexpr size_t F_GATE2 = F_GATE1 + K1N;              // K2N
constexpr size_t F_DIS0  = F_GATE2 + K2N;              // (unused)
constexpr size_t F_DIS1  = F_DIS0 + N0;                // K1N
constexpr size_t F_DIS2  = F_DIS1 + K1N;               // K2N
constexpr size_t F_PERM1 = F_DIS2 + K2N;               // K1N (int)
constexpr size_t F_PERM2 = F_PERM1 + K1N;              // K2N (int)
constexpr size_t F_INV1  = F_PERM2 + K2N;              // N0  (int)
constexpr size_t F_INV2  = F_INV1 + N0;                // K1N (int)
constexpr size_t F_CNTI  = F_INV2 + K1N;               // N0  (int)
constexpr size_t F_CNTO  = F_CNTI + N0;                // N0  (int) (unused)
constexpr size_t F_SELF  = F_CNTO + N0;                // N0  (int)
constexpr size_t F_CI    = F_SELF + N0;                // N0*CAP (int)
constexpr size_t F_CO    = F_CI + (size_t)N0 * CAP;    // N0*CAP (int) (unused)
constexpr size_t F_CSRN  = F_CO + (size_t)N0 * CAP;    // K1N (int)
constexpr size_t F_CSRK  = F_CSRN + K1N;               // K1N*RCAP (int)
constexpr size_t F_CSRW  = F_CSRK + (size_t)K1N * RCAP;// K1N*RCAP (float)
constexpr size_t F_END   = F_CSRW + (size_t)K1N * RCAP;

// ---------------- init (fills) ----------------
__global__ void k_init(float* __restrict__ gate, int* __restrict__ perm,
                       int* __restrict__ inv, int* __restrict__ cnt,
                       float* __restrict__ outlab) {
  int i = blockIdx.x * blockDim.x + threadIdx.x, st = gridDim.x * blockDim.x;
  for (int j = i; j < K1N + K2N; j += st) gate[j] = 0.0f;
  for (int j = i; j < K1N + K2N; j += st) perm[j] = 0;
  for (int j = i; j < N0 + K1N; j += st) inv[j] = -1;
  for (int j = i; j < 3 * N0; j += st) cnt[j] = 0;
  for (int j = i; j < N0 * 29; j += st) outlab[j] = 0.0f;
}

// ---------------- shared yw2 tile body (UNSCALED output) ----------------
struct __align__(16) YWShared { float Wt[32 * HID]; float Xt[32 * ATS]; };

__device__ __forceinline__ void yw2_body(YWShared* sm, int bid,
                                         const float* __restrict__ X,
                                         const float* __restrict__ X2,
                                         const int* __restrict__ inv2c,
                                         int Kin, int nsrc, int n,
                                         const float* __restrict__ Wm,
                                         const int* __restrict__ perm,
                                         float* __restrict__ Ysc) {
  int t = threadIdx.x;
  int r0 = bid * BM;
  int f4 = (t & 31) * 4;
  int rg = t >> 5;
  float4 acc0 = {0,0,0,0}, acc1 = {0,0,0,0}, acc2 = {0,0,0,0}, acc3 = {0,0,0,0};
  for (int kb = 0; kb < Kin; kb += 32) {
    {
      const float4* src = (const float4*)(Wm + (size_t)kb * HID);
      float4* dst = (float4*)sm->Wt;
#pragma unroll
      for (int i = 0; i < 4; ++i) dst[i * 256 + t] = src[i * 256 + t];
    }
    {
      int j = t >> 3;
      int k4 = (t & 7) * 4;
      int r = r0 + j;
      int src_row = (r < n) ? r : (n - 1);
      if (perm) {
        int s = perm[src_row];
        if (s < 0) s = 0;
        if (s >= nsrc) s = nsrc - 1;
        src_row = s;
      }
      float4 xv = *(const float4*)(X + (size_t)src_row * Kin + kb + k4);
      if (X2) {
        int ii = inv2c[src_row];
        if (ii >= 0 && ii < K2N) {
          float4 x2 = *(const float4*)(X2 + (size_t)ii * Kin + kb + k4);
          xv.x += x2.x; xv.y += x2.y; xv.z += x2.z; xv.w += x2.w;
        }
      }
      sm->Xt[(k4 + 0) * ATS + j] = xv.x;
      sm->Xt[(k4 + 1) * ATS + j] = xv.y;
      sm->Xt[(k4 + 2) * ATS + j] = xv.z;
      sm->Xt[(k4 + 3) * ATS + j] = xv.w;
    }
    __syncthreads();
#pragma unroll 4
    for (int kk = 0; kk < 32; ++kk) {
      float4 y = *(const float4*)&sm->Wt[kk * HID + f4];
      float4 a = *(const float4*)&sm->Xt[kk * ATS + rg * 4];
      acc0.x += a.x * y.x; acc0.y += a.x * y.y; acc0.z += a.x * y.z; acc0.w += a.x * y.w;
      acc1.x += a.y * y.x; acc1.y += a.y * y.y; acc1.z += a.y * y.z; acc1.w += a.y * y.w;
      acc2.x += a.z * y.x; acc2.y += a.z * y.y; acc2.z += a.z * y.z; acc2.w += a.z * y.w;
      acc3.x += a.w * y.x; acc3.y += a.w * y.y; acc3.z += a.w * y.z; acc3.w += a.w * y.w;
    }
    __syncthreads();
  }
  int r = r0 + rg * 4;
  float4* accs[4] = {&acc0, &acc1, &acc2, &acc3};
#pragma unroll
  for (int j = 0; j < 4; ++j) {
    int row = r + j;
    if (row >= n) continue;
    *(float4*)&Ysc[(size_t)row * HID + f4] = *accs[j];
  }
}

// ---------------- edge count + yw2-L0 (merged, independent block ranges) ----------------
__global__ __launch_bounds__(256) void k_cntyw(const int* __restrict__ ei,
                                               int* cnt_in, int* selfc, int* col_in,
                                               const float* __restrict__ x,
                                               const float* __restrict__ Wd0,
                                               float* __restrict__ Ysc) {
  __shared__ YWShared smy;
  int b = blockIdx.x;
  if (b < NBC) {
    int e = b * 256 + threadIdx.x;
    if (e < E0) {
      int s = ei[e], d = ei[E0 + e];
      if (s == d) { atomicAdd(&selfc[d], 1); }
      else {
        int a = atomicAdd(&cnt_in[d], 1);
        if (a < CAP) col_in[d * CAP + a] = s;
      }
    }
    return;
  }
  yw2_body(&smy, b - NBC, x, nullptr, nullptr, 32, N0, N0, Wd0, nullptr, Ysc);
}

// ---------------- level-0 sparse GCN + score (src-side scale applied here) ----------------
__global__ void k_gcn_sparse(const float* __restrict__ Yraw, const int* __restrict__ cnt_in,
                             const int* __restrict__ col_in, const int* __restrict__ selfc,
                             const float* __restrict__ bias, const float* __restrict__ p,
                             float* __restrict__ H, float* __restrict__ score) {
  __shared__ float red[HID];
  __shared__ float red2[HID];
  int d = blockIdx.x, f = threadIdx.x;
  int cntu = cnt_in[d];
  int cnt = cntu > CAP ? CAP : cntu;
  int scd = selfc[d];
  float d0d = 1.0f / sqrtf((float)(cntu + scd + 2));
  float yd = d0d * Yraw[(size_t)d * HID + f];
  float acc = (2.0f + (float)scd) * yd;
  int e = 0;
  for (; e + 8 <= cnt; e += 8) {
    int cols[8];
#pragma unroll
    for (int j = 0; j < 8; ++j) cols[j] = col_in[d * CAP + e + j];
    float s[8];
#pragma unroll
    for (int j = 0; j < 8; ++j)
      s[j] = 1.0f / sqrtf((float)(cnt_in[cols[j]] + selfc[cols[j]] + 2));
    float y[8];
#pragma unroll
    for (int j = 0; j < 8; ++j) y[j] = s[j] * Yraw[(size_t)cols[j] * HID + f];
#pragma unroll
    for (int j = 0; j < 8; ++j) acc += y[j];
  }
  for (; e < cnt; ++e) {
    int c = col_in[d * CAP + e];
    float s = 1.0f / sqrtf((float)(cnt_in[c] + selfc[c] + 2));
    acc += s * Yraw[(size_t)c * HID + f];
  }
  float h = tanhf(d0d * acc + bias[f]);
  H[(size_t)d * HID + f] = h;
  float pv = p[f];
  red[f] = h * pv;
  red2[f] = pv * pv;
  __syncthreads();
  for (int s = 64; s > 0; s >>= 1) {
    if (f < s) { red[f] += red[f + s]; red2[f] += red2[f + s]; }
    __syncthreads();
  }
  if (f == 0) score[d] = tanhf(red[0] * (1.0f / sqrtf(red2[0])));
}

// ---------------- top-K (round-1 verified) ----------------
__global__ __launch_bounds__(TKT) void k_topk(const float* __restrict__ score, int n, int K,
                                              int* __restrict__ perm, float* __restrict__ gatec,
                                              int* __restrict__ inv) {
  __shared__ unsigned setA[N0];
  __shared__ unsigned setB[N0];
  __shared__ int hist[256];
  __shared__ int sscan[257];
  __shared__ unsigned pfx_sh;
  __shared__ int rem_sh;
  __shared__ int cnt_sh;
  __shared__ int cgt[48], ceq[48], bgt[48], beq[48];
  int t = threadIdx.x;
  int lane = t & 63, wv = t >> 6;
  unsigned long long below = (lane == 0) ? 0ull : (~0ull >> (64 - lane));
  for (int i = t; i < n; i += TKT) setA[i] = fkey(score[i]);
  __syncthreads();

  unsigned prefix = 0; int rem = K; int m = n;
  unsigned* cur = setA; unsigned* nxt = setB;
  for (int pass = 3; pass >= 0; --pass) {
    if (t < 256) hist[t] = 0;
    __syncthreads();
    for (int i = t; i < m; i += TKT) atomicAdd(&hist[(cur[i] >> (pass * 8)) & 255], 1);
    __syncthreads();
    if (t < 256) { sscan[t] = hist[t]; if (t == 0) sscan[256] = 0; }
    __syncthreads();
    for (int off = 1; off < 256; off <<= 1) {
      int add = 0;
      if (t < 256) add = (t + off < 256) ? sscan[t + off] : 0;
      __syncthreads();
      if (t < 256) sscan[t] += add;
      __syncthreads();
    }
    if (t < 256 && sscan[t] >= rem && sscan[t + 1] < rem) {
      pfx_sh = prefix | ((unsigned)t << (pass * 8));
      rem_sh = rem - sscan[t + 1];
    }
    __syncthreads();
    prefix = pfx_sh; rem = rem_sh;
    if (pass > 0) {
      unsigned dg = (prefix >> (pass * 8)) & 255u;
      if (t == 0) cnt_sh = 0;
      __syncthreads();
      for (int c0 = 0; c0 < m; c0 += TKT) {
        int i = c0 + t;
        unsigned u = (i < m) ? cur[i] : 0u;
        bool match = (i < m) && (((u >> (pass * 8)) & 255u) == dg);
        unsigned long long mm = __ballot(match);
        int cw = (int)__popcll(mm);
        int basew = 0;
        if (lane == 0 && cw) basew = atomicAdd(&cnt_sh, cw);
        basew = __shfl(basew, 0);
        if (match) nxt[basew + (int)__popcll(mm & below)] = u;
      }
      __syncthreads();
      m = cnt_sh;
      unsigned* tmp = cur; cur = nxt; nxt = tmp;
    }
  }
  unsigned uthr = prefix;
  int c_gt = K - rem;
  int NC = (n + 63) >> 6;
  for (int c = wv; c < NC; c += 16) {
    int i = (c << 6) + lane;
    unsigned u = (i < n) ? fkey(score[i]) : 0u;
    bool isgt = (i < n) && (u > uthr);
    bool iseq = (i < n) && (u == uthr);
    unsigned long long mg = __ballot(isgt);
    unsigned long long me = __ballot(iseq);
    if (lane == 0) { cgt[c] = (int)__popcll(mg); ceq[c] = (int)__popcll(me); }
  }
  __syncthreads();
  if (t == 0) {
    int g = 0, e = 0;
    for (int c = 0; c < NC; ++c) { bgt[c] = g; g += cgt[c]; beq[c] = e; e += ceq[c]; }
  }
  __syncthreads();
  for (int c = wv; c < NC; c += 16) {
    int i = (c << 6) + lane;
    unsigned u = (i < n) ? fkey(score[i]) : 0u;
    bool isgt = (i < n) && (u > uthr);
    bool iseq = (i < n) && (u == uthr);
    unsigned long long mg = __ballot(isgt);
    unsigned long long me = __ballot(iseq);
    if (isgt) {
      int pos = bgt[c] + (int)__popcll(mg & below);
      perm[pos] = i; gatec[pos] = inv_fkey(u); inv[i] = pos;
    } else if (iseq) {
      int er = beq[c] + (int)__popcll(me & below);
      if (er < rem) { int pos = c_gt + er; perm[pos] = i; gatec[pos] = inv_fkey(u); inv[i] = pos; }
    }
  }
}

// ---------------- A1 rows -> CSR + dis1 (blocks < K1N)  ||  yw2-L1 (rest) ----------------
union RowAU {
  struct { int row[K1N]; int cntw[4]; int wsum; } rc;
  YWShared yw;
};

__global__ __launch_bounds__(256) void k_rowA(const int* __restrict__ perm1,
                                              const int* __restrict__ inv1,
                                              const int* __restrict__ cnt_in,
                                              const int* __restrict__ col_in,
                                              int* __restrict__ csr_n,
                                              int* __restrict__ csr_k,
                                              float* __restrict__ csr_w,
                                              float* __restrict__ dis1,
                                              const float* __restrict__ h0,
                                              const float* __restrict__ Wd1,
                                              float* __restrict__ Ysc) {
  __shared__ RowAU sm;
  int b = blockIdx.x, t = threadIdx.x;
  if (b >= K1N) {
    yw2_body(&sm.yw, b - K1N, h0, nullptr, nullptr, HID, N0, K1N, Wd1, perm1, Ysc);
    return;
  }
  int r = b;
  for (int i = t; i < K1N; i += 256) sm.rc.row[i] = 0;
  if (t == 0) sm.rc.wsum = 0;
  __syncthreads();
  int d = perm1[r];
  int ni = cnt_in[d]; if (ni > CAP) ni = CAP;
  if (t < ni) {
    int s = col_in[d * CAP + t];
    int jj = inv1[s];
    if (jj >= 0) atomicAdd(&sm.rc.row[jj], 2);
  }
  {
    int ta = t >> 3, tb = t & 7;
    for (int a = ta; a < ni; a += 32) {
      int m = col_in[d * CAP + a];
      int nm = cnt_in[m]; if (nm > CAP) nm = CAP;
      for (int bq = tb; bq < nm; bq += 8) {
        int s = col_in[m * CAP + bq];
        if (s != d) {
          int jj = inv1[s];
          if (jj >= 0) atomicAdd(&sm.rc.row[jj], 1);
        }
      }
    }
  }
  __syncthreads();
  int wid = t >> 6, lane = t & 63;
  unsigned long long below = (lane == 0) ? 0ull : (~0ull >> (64 - lane));
  int base = 0, ws = 0;
  int* gk = csr_k + (size_t)r * RCAP;
  float* gw = csr_w + (size_t)r * RCAP;
  for (int c0 = 0; c0 < K1N; c0 += 256) {
    int col = c0 + t;
    int v = (col < K1N) ? sm.rc.row[col] : 0;
    ws += v;
    bool nz = (v != 0);
    unsigned long long m = __ballot(nz);
    if (lane == 0) sm.rc.cntw[wid] = (int)__popcll(m);
    __syncthreads();
    int pref = 0;
#pragma unroll
    for (int w = 0; w < 4; ++w) if (w < wid) pref += sm.rc.cntw[w];
    int pos = base + pref + (int)__popcll(m & below);
    if (nz) { gk[pos] = col; gw[pos] = (float)v; }
    base += sm.rc.cntw[0] + sm.rc.cntw[1] + sm.rc.cntw[2] + sm.rc.cntw[3];
    __syncthreads();
  }
  for (int off = 32; off > 0; off >>= 1) ws += __shfl_down(ws, off);
  if (lane == 0) atomicAdd(&sm.rc.wsum, ws);
  __syncthreads();
  if (t == 0) {
    csr_n[r] = base;
    dis1[r] = 1.0f / sqrtf((float)sm.rc.wsum + 2.0f);
  }
}

// ---------------- CSR spmv + epilogue (+ score); src scale s=dis[col]*gate[col] ----------------
__global__ __launch_bounds__(128) void k_spmv_csr(const int* __restrict__ csr_n,
                                                  const int* __restrict__ csr_k,
                                                  const float* __restrict__ csr_w,
                                                  const float* __restrict__ Yraw,
                                                  const float* __restrict__ dis,
                                                  const float* __restrict__ gate,
                                                  const float* __restrict__ bias,
                                                  const float* __restrict__ p,
                                                  float* __restrict__ H,
                                                  float* __restrict__ score, int act) {
  __shared__ float red[HID];
  __shared__ float red2[HID];
  int r = blockIdx.x, t = threadIdx.x;
  int nnz = csr_n[r];
  const int* gk = csr_k + (size_t)r * RCAP;
  const float* gw = csr_w + (size_t)r * RCAP;
  float acc = 0.0f;
  int pp = 0;
  for (; pp + 8 <= nnz; pp += 8) {
    int kk[8]; float ww[8], ss[8], y[8];
#pragma unroll
    for (int j = 0; j < 8; ++j) kk[j] = gk[pp + j];
#pragma unroll
    for (int j = 0; j < 8; ++j) ww[j] = gw[pp + j];
#pragma unroll
    for (int j = 0; j < 8; ++j) ss[j] = gate ? dis[kk[j]] * gate[kk[j]] : dis[kk[j]];
#pragma unroll
    for (int j = 0; j < 8; ++j) y[j] = ss[j] * Yraw[(size_t)kk[j] * HID + t];
#pragma unroll
    for (int j = 0; j < 8; ++j) acc += ww[j] * y[j];
  }
  for (; pp < nnz; ++pp) {
    int k = gk[pp];
    float s = gate ? dis[k] * gate[k] : dis[k];
    acc += gw[pp] * (s * Yraw[(size_t)k * HID + t]);
  }
  float sr = gate ? dis[r] * gate[r] : dis[r];
  float yr = sr * Yraw[(size_t)r * HID + t];
  float zv = dis[r] * (acc + 2.0f * yr) + bias[t];
  float h = act ? tanhf(zv) : zv;
  H[(size_t)r * HID + t] = h;
  if (p) {
    float pv = p[t];
    red[t] = h * pv;
    red2[t] = pv * pv;
    __syncthreads();
    for (int s = 64; s > 0; s >>= 1) {
      if (t < s) { red[t] += red[t + s]; red2[t] += red2[t + s]; }
      __syncthreads();
    }
    if (t == 0) score[r] = tanhf(red[0] * (1.0f / sqrtf(red2[0])));
  }
}

// ---------------- Ac build from CSR (blocks < K1N)  ||  yw2-L2 (rest) ----------------
__global__ __launch_bounds__(256) void k_cmpyw(const int* __restrict__ csr_n,
                                               const int* __restrict__ csr_k,
                                               const float* __restrict__ csr_w,
                                               const int* __restrict__ inv2,
                                               short* __restrict__ Ac,
                                               const float* __restrict__ h1,
                                               const float* __restrict__ Wd2,
                                               const int* __restrict__ perm2,
                                               float* __restrict__ Ysc) {
  __shared__ YWShared smy;
  int b = blockIdx.x, t = threadIdx.x;
  if (b >= K1N) {
    yw2_body(&smy, b - K1N, h1, nullptr, nullptr, HID, K1N, K2N, Wd2, perm2, Ysc);
    return;
  }
  short* dst = Ac + (size_t)b * LD2;
  for (int i = t; i < LD2; i += 256) dst[i] = 0;
  __syncthreads();
  int nnz = csr_n[b];
  const int* gk = csr_k + (size_t)b * RCAP;
  const float* gw = csr_w + (size_t)b * RCAP;
  for (int i = t; i < nnz; i += 256) {
    int c = inv2[gk[i]];
    if (c >= 0) dst[c] = (short)gw[i];
  }
}

// ---------------- A2 + dis2 (Ac-only; de-staged CSR reads) ----------------
__global__ __launch_bounds__(192) void k_sq2(const short* __restrict__ Ac,
                                             const int* __restrict__ perm2,
                                             const int* __restrict__ csr_n,
                                             const int* __restrict__ csr_k,
                                             const float* __restrict__ csr_w,
                                             float* __restrict__ A2,
                                             float* __restrict__ dis2) {
  __shared__ float wred[3];
  int a = blockIdx.x, t = threadIdx.x;
  int qa = perm2[a];
  if (qa < 0) qa = 0;
  if (qa >= K1N) qa = K1N - 1;
  const short* acq = Ac + (size_t)qa * LD2;
  int nnz = csr_n[qa];
  const int* gk = csr_k + (size_t)qa * RCAP;
  const float* gw = csr_w + (size_t)qa * RCAP;
  int c0 = t * 4;                     // 0..764, always in-range
  float4 acc = make_float4(0.f, 0.f, 0.f, 0.f);
  int p = 0;
  for (; p + 8 <= nnz; p += 8) {
    int kk[8]; float ww[8];
#pragma unroll
    for (int j = 0; j < 8; ++j) { kk[j] = gk[p + j]; ww[j] = gw[p + j]; }
    short4 v[8];
#pragma unroll
    for (int j = 0; j < 8; ++j) v[j] = *(const short4*)&Ac[(size_t)kk[j] * LD2 + c0];
#pragma unroll
    for (int j = 0; j < 8; ++j) {
      acc.x += ww[j] * (float)v[j].x;
      acc.y += ww[j] * (float)v[j].y;
      acc.z += ww[j] * (float)v[j].z;
      acc.w += ww[j] * (float)v[j].w;
    }
  }
  for (; p < nnz; ++p) {
    int k = gk[p]; float w = gw[p];
    short4 v = *(const short4*)&Ac[(size_t)k * LD2 + c0];
    acc.x += w * (float)v.x; acc.y += w * (float)v.y;
    acc.z += w * (float)v.z; acc.w += w * (float)v.w;
  }
  float rsum = 0.0f;
  {
    float accv[4] = {acc.x, acc.y, acc.z, acc.w};
    float outv[4];
#pragma unroll
    for (int j = 0; j < 4; ++j) {
      int col = c0 + j;
      float v = 0.0f;
      if (col < K2N && col != a) {
        v = accv[j] + 2.0f * (float)acq[col];
      }
      outv[j] = v;
      rsum += v;
    }
    *(float4*)&A2[(size_t)a * LD2 + c0] = make_float4(outv[0], outv[1], outv[2], outv[3]);
  }
  for (int off = 32; off > 0; off >>= 1) rsum += __shfl_down(rsum, off);
  if ((t & 63) == 0) wred[t >> 6] = rsum;
  __syncthreads();
  if (t == 0) dis2[a] = 1.0f / sqrtf(wred[0] + wred[1] + wred[2] + 2.0f);
}

// ---------------- dense direct spmv on A2 (src scale s2=dis2*gate2) ----------------
__global__ __launch_bounds__(128) void k_spmv2(const float* __restrict__ A2,
                                               const float* __restrict__ Yraw,
                                               const float* __restrict__ dis2,
                                               const float* __restrict__ gate2,
                                               const float* __restrict__ bias,
                                               float* __restrict__ H) {
  int r = blockIdx.x, t = threadIdx.x;
  const float* arow = A2 + (size_t)r * LD2;
  float acc = 0.0f;
  int c = 0;
  for (; c + 8 <= K2N; c += 8) {
    float w[8], s[8], y[8];
#pragma unroll
    for (int j = 0; j < 8; ++j) w[j] = arow[c + j];
#pragma unroll
    for (int j = 0; j < 8; ++j) s[j] = dis2[c + j] * gate2[c + j];
#pragma unroll
    for (int j = 0; j < 8; ++j) y[j] = s[j] * Yraw[(size_t)(c + j) * HID + t];
#pragma unroll
    for (int j = 0; j < 8; ++j) acc += w[j] * y[j];
  }
  for (; c < K2N; ++c) {
    float s = dis2[c] * gate2[c];
    acc += arow[c] * (s * Yraw[(size_t)c * HID + t]);
  }
  float s2r = dis2[r] * gate2[r];
  float yr = s2r * Yraw[(size_t)r * HID + t];
  float zv = dis2[r] * (acc + 2.0f * yr) + bias[t];
  H[(size_t)r * HID + t] = tanhf(zv);
}

// ---------------- up-path yw2 (combine h1 + scatter(h2)), unscaled ----------------
__global__ __launch_bounds__(256) void k_ywup(const float* __restrict__ h1,
                                              const float* __restrict__ h2,
                                              const int* __restrict__ inv2,
                                              const float* __restrict__ Wu0,
                                              float* __restrict__ Ysc) {
  __shared__ YWShared smy;
  yw2_body(&smy, blockIdx.x, h1, h2, inv2, HID, K1N, K1N, Wu0, nullptr, Ysc);
}

// ---------------- Yf + final (unchanged, round-3 verified) ----------------
__global__ void k_yf(const float* __restrict__ h0, const float* __restrict__ u1b,
                     const int* __restrict__ inv1, const float* __restrict__ Wup1,
                     const int* __restrict__ cnt_in, const int* __restrict__ selfc,
                     float* __restrict__ Yfsc) {
  __shared__ float red[3][HID];
  int i = blockIdx.x, t = threadIdx.x;
  float v = h0[i * HID + t];
  int ii = inv1[i];
  if (ii >= 0 && ii < K1N) v += u1b[ii * HID + t];
#pragma unroll
  for (int c = 0; c < 3; ++c) red[c][t] = v * Wup1[t * 3 + c];
  __syncthreads();
  for (int s = 64; s > 0; s >>= 1) {
    if (t < s) { red[0][t] += red[0][t + s]; red[1][t] += red[1][t + s]; red[2][t] += red[2][t + s]; }
    __syncthreads();
  }
  if (t < 3) {
    float d0 = 1.0f / sqrtf((float)(cnt_in[i] + selfc[i] + 2));
    Yfsc[i * 3 + t] = d0 * red[t][0];
  }
}

__global__ void k_final(const float* __restrict__ Yfsc, const int* __restrict__ cnt_in,
                        const int* __restrict__ col_in, const int* __restrict__ selfc,
                        const float* __restrict__ bup1, const float* __restrict__ z,
                        float* __restrict__ out) {
  int idx = blockIdx.x * blockDim.x + threadIdx.x;
  if (idx >= N0 * 3) return;
  int d = idx / 3, c = idx - d * 3;
  int cntu = cnt_in[d];
  int cnt = cntu > CAP ? CAP : cntu;
  float acc = (2.0f + (float)selfc[d]) * Yfsc[d * 3 + c];
  int e = 0;
  for (; e + 8 <= cnt; e += 8) {
    float y[8];
#pragma unroll
    for (int j = 0; j < 8; ++j) y[j] = Yfsc[col_in[d * CAP + e + j] * 3 + c];
#pragma unroll
    for (int j = 0; j < 8; ++j) acc += y[j];
  }
  for (; e < cnt; ++e) acc += Yfsc[col_in[d * CAP + e] * 3 + c];
  float d0 = 1.0f / sqrtf((float)(cntu + selfc[d] + 2));
  out[idx] = d0 * acc + bup1[c] + 0.1f * z[idx];
}

extern "C" void kernel_launch(void* const* d_in, const int* in_sizes, int n_in,
                              void* d_out, int out_size, void* d_ws, size_t ws_size,
                              hipStream_t stream) {
  const float* x   = (const float*)d_in[0];
  const float* z   = (const float*)d_in[1];
  const float* Wd0 = (const float*)d_in[2];
  const float* bd0 = (const float*)d_in[3];
  const float* Wd1 = (const float*)d_in[4];
  const float* bd1 = (const float*)d_in[5];
  const float* Wd2 = (const float*)d_in[6];
  const float* bd2 = (const float*)d_in[7];
  const float* p1  = (const float*)d_in[8];
  const float* p2  = (const float*)d_in[9];
  const float* Wu0 = (const float*)d_in[10];
  const float* bu0 = (const float*)d_in[11];
  const float* Wu1 = (const float*)d_in[12];
  const float* bu1 = (const float*)d_in[13];
  const int*   ei  = (const int*)d_in[14];

  if (ws_size < F_END * sizeof(float)) return;

  float* W     = (float*)d_ws;
  short* Ac    = (short*)(W + F_SCR);
  float* A2    = W + F_A2;
  float* Ysc   = W + F_YSC;
  float* h0    = W + F_H0;
  float* h1    = W + F_H1;
  float* h2    = W + F_H2;
  float* u1b   = W + F_U1B;
  float* Yfsc  = W + F_YF;
  float* score = W + F_SCORE;
  float* gate1 = W + F_GATE1;
  float* gate2 = W + F_GATE2;
  float* dis1  = W + F_DIS1;
  float* dis2  = W + F_DIS2;
  int* perm1   = (int*)(W + F_PERM1);
  int* perm2   = (int*)(W + F_PERM2);
  int* inv1    = (int*)(W + F_INV1);
  int* inv2    = (int*)(W + F_INV2);
  int* cnt_in  = (int*)(W + F_CNTI);
  int* selfc   = (int*)(W + F_SELF);
  int* col_in  = (int*)(W + F_CI);
  int* csr_n   = (int*)(W + F_CSRN);
  int* csr_k   = (int*)(W + F_CSRK);
  float* csr_w = W + F_CSRW;
  float* out   = (float*)d_out;

  // 1. fills
  k_init<<<128, 256, 0, stream>>>(gate1, perm1, inv1, cnt_in, out + N0 * 3);
  // 2. edge lists || level-0 YW (unscaled)
  k_cntyw<<<NBC + NBY0, 256, 0, stream>>>(ei, cnt_in, selfc, col_in, x, Wd0, Ysc);
  // 3. level-0 GCN + pool-1 score (scale fused here)
  k_gcn_sparse<<<N0, HID, 0, stream>>>(Ysc, cnt_in, col_in, selfc, bd0, p1, h0, score);
  // 4. top-K #1
  k_topk<<<1, TKT, 0, stream>>>(score, N0, K1N, perm1, gate1, inv1);
  // 5. A1 CSR + dis1 || level-1 YW (unscaled)
  k_rowA<<<K1N + NBY1, 256, 0, stream>>>(perm1, inv1, cnt_in, col_in,
                                         csr_n, csr_k, csr_w, dis1, h0, Wd1, Ysc);
  // 6. level-1 spmv + pool-2 score (scale fused)
  k_spmv_csr<<<K1N, 128, 0, stream>>>(csr_n, csr_k, csr_w, Ysc, dis1, gate1, bd1, p2,
                                      h1, score, 1);
  // 7. top-K #2
  k_topk<<<1, TKT, 0, stream>>>(score, K1N, K2N, perm2, gate2, inv2);
  // 8. Ac scatter-build || level-2 YW (unscaled)
  k_cmpyw<<<K1N + NBY2, 256, 0, stream>>>(csr_n, csr_k, csr_w, inv2, Ac, h1, Wd2, perm2, Ysc);
  // 9. A2 + dis2
  k_sq2<<<K2N, 192, 0, stream>>>(Ac, perm2, csr_n, csr_k, csr_w, A2, dis2);
  // 10. level-2 dense spmv (scale fused)
  k_spmv2<<<K2N, 128, 0, stream>>>(A2, Ysc, dis2, gate2, bd2, h2);
  // 11. up-path YW (combine h1 + scatter h2, unscaled)
  k_ywup<<<NBY1, 256, 0, stream>>>(h1, h2, inv2, Wu0, Ysc);
  // 12. up-path spmv (scale = dis1 only)
  k_spmv_csr<<<K1N, 128, 0, stream>>>(csr_n, csr_k, csr_w, Ysc, dis1, nullptr, bu0, nullptr,
                                      u1b, nullptr, 1);
  // 13. Yf
  k_yf<<<N0, HID, 0, stream>>>(h0, u1b, inv1, Wu1, cnt_in, selfc, Yfsc);
  // 14. final
  k_final<<<(N0 * 3 + 255) / 256, 256, 0, stream>>>(Yfsc, cnt_in, col_in, selfc, bu1, z, out);
}

// Round 5
// 242.964 us; speedup vs baseline: 1.1420x; 1.1420x over previous
//
#include <hip/hip_runtime.h>
#include <hip/hip_bf16.h>

#define N0   3000
#define E0   48000
#define K1N  1500
#define K2N  750
#define HID  128
#define CAP  128
#define LD1  1536  // (A1 dense retired; offset kept for layout compat)
#define LD2  768   // padded leading dim for A2/Ac
#define BM   32    // row-tile for k_yw2
#define ATS  36    // transposed X-tile stride (BM+4, bank-spread)
#define RCAP 1536  // CSR row capacity (>= max possible nnz = K1N)
#define TKT  1024  // k_topk threads (16 waves on one CU)

__device__ __forceinline__ unsigned fkey(float f) {
  unsigned u = __float_as_uint(f);
  return (u & 0x80000000u) ? ~u : (u | 0x80000000u);
}
__device__ __forceinline__ float inv_fkey(unsigned u) {
  unsigned v = (u & 0x80000000u) ? (u & 0x7FFFFFFFu) : ~u;
  return __uint_as_float(v);
}

// ---------------- workspace layout (float units) ----------------
constexpr size_t F_A1    = 0;                          // retired (hole, layout compat)
constexpr size_t F_SCR   = F_A1 + (size_t)K1N * LD1;   // Ac (int16) = K1N*LD2 shorts
constexpr size_t SCR_SZ  = 1155072;
constexpr size_t F_A2    = F_SCR + SCR_SZ;             // K2N*LD2
constexpr size_t F_YSC   = F_A2 + (size_t)K2N * LD2;   // N0*HID
constexpr size_t F_H0    = F_YSC + (size_t)N0 * HID;   // N0*HID
constexpr size_t F_H1    = F_H0 + (size_t)N0 * HID;    // K1N*HID
constexpr size_t F_H2    = F_H1 + (size_t)K1N * HID;   // K2N*HID
constexpr size_t F_U1    = F_H2 + (size_t)K2N * HID;   // (hole)
constexpr size_t F_U1B   = F_U1 + (size_t)K1N * HID;   // K1N*HID
constexpr size_t F_YF    = F_U1B + (size_t)K1N * HID;  // N0*3
constexpr size_t F_SCORE = F_YF + (size_t)N0 * 3;      // N0
constexpr size_t F_GATE1 = F_SCORE + N0;               // K1N
constexpr size_t F_GATE2 = F_GATE1 + K1N;              // K2N
constexpr size_t F_DIS0  = F_GATE2 + K2N;              // (unused)
constexpr size_t F_DIS1  = F_DIS0 + N0;                // K1N
constexpr size_t F_DIS2  = F_DIS1 + K1N;               // K2N
constexpr size_t F_PERM1 = F_DIS2 + K2N;               // K1N (int)
constexpr size_t F_PERM2 = F_PERM1 + K1N;              // K2N (int)
constexpr size_t F_INV1  = F_PERM2 + K2N;              // N0  (int)
constexpr size_t F_INV2  = F_INV1 + N0;                // K1N (int)
constexpr size_t F_CNTI  = F_INV2 + K1N;               // N0  (int)
constexpr size_t F_CNTO  = F_CNTI + N0;                // N0  (int) (unused)
constexpr size_t F_SELF  = F_CNTO + N0;                // N0  (int)
constexpr size_t F_CI    = F_SELF + N0;                // N0*CAP (int)
constexpr size_t F_CO    = F_CI + (size_t)N0 * CAP;    // N0*CAP (int) (unused)
constexpr size_t F_CSRN  = F_CO + (size_t)N0 * CAP;    // K1N (int)
constexpr size_t F_CSRK  = F_CSRN + K1N;               // K1N*RCAP (int)
constexpr size_t F_CSRW  = F_CSRK + (size_t)K1N * RCAP;// K1N*RCAP (float)
constexpr size_t F_END   = F_CSRW + (size_t)K1N * RCAP;

// ---------------- init: small fills only ----------------
__global__ void k_init(float* __restrict__ gate, int* __restrict__ perm,
                       int* __restrict__ inv, int* __restrict__ cnt,
                       float* __restrict__ outlab) {
  int i = blockIdx.x * blockDim.x + threadIdx.x, st = gridDim.x * blockDim.x;
  for (int j = i; j < K1N + K2N; j += st) gate[j] = 0.0f;
  for (int j = i; j < K1N + K2N; j += st) perm[j] = 0;
  for (int j = i; j < N0 + K1N; j += st) inv[j] = -1;
  for (int j = i; j < 3 * N0; j += st) cnt[j] = 0;
  for (int j = i; j < N0 * 29; j += st) outlab[j] = 0.0f;
}

// Build per-node in-edge lists.
__global__ void k_count(const int* __restrict__ ei, int* cnt_in, int* selfc, int* col_in) {
  int e = blockIdx.x * blockDim.x + threadIdx.x;
  if (e >= E0) return;
  int s = ei[e], d = ei[E0 + e];
  if (s == d) { atomicAdd(&selfc[d], 1); return; }
  int a = atomicAdd(&cnt_in[d], 1);
  if (a < CAP) col_in[d * CAP + a] = s;
}

// Ysc[row][f] = scale(row) * sum_k Xeff[src(row)][k] * Wm[k][f]
__global__ __launch_bounds__(256) void k_yw2(const float* __restrict__ X,
                                             const float* __restrict__ X2,
                                             const int* __restrict__ inv2c,
                                             int Kin, int nsrc, int n,
                                             const float* __restrict__ Wm,
                                             const int* __restrict__ perm,
                                             const float* __restrict__ gate,
                                             const float* __restrict__ dis,
                                             const int* __restrict__ cntd,
                                             const int* __restrict__ selfd,
                                             float* __restrict__ Ysc) {
  __shared__ float Wt[32 * HID];   // 16 KB, [kk][f]
  __shared__ float Xt[32 * ATS];   // 4.6 KB, [kk][row] transposed
  int t = threadIdx.x;
  int r0 = blockIdx.x * BM;
  int f4 = (t & 31) * 4;
  int rg = t >> 5;                 // 0..7 -> rows r0 + rg*4 + {0..3}
  float4 acc0 = {0,0,0,0}, acc1 = {0,0,0,0}, acc2 = {0,0,0,0}, acc3 = {0,0,0,0};
  for (int kb = 0; kb < Kin; kb += 32) {
    {
      const float4* src = (const float4*)(Wm + (size_t)kb * HID);
      float4* dst = (float4*)Wt;
#pragma unroll
      for (int i = 0; i < 4; ++i) dst[i * 256 + t] = src[i * 256 + t];
    }
    {
      int j = t >> 3;
      int k4 = (t & 7) * 4;
      int r = r0 + j;
      int src_row = (r < n) ? r : (n - 1);
      if (perm) {
        int s = perm[src_row];
        if (s < 0) s = 0;
        if (s >= nsrc) s = nsrc - 1;
        src_row = s;
      }
      float4 xv = *(const float4*)(X + (size_t)src_row * Kin + kb + k4);
      if (X2) {
        int ii = inv2c[src_row];
        if (ii >= 0 && ii < K2N) {
          float4 x2 = *(const float4*)(X2 + (size_t)ii * Kin + kb + k4);
          xv.x += x2.x; xv.y += x2.y; xv.z += x2.z; xv.w += x2.w;
        }
      }
      Xt[(k4 + 0) * ATS + j] = xv.x;
      Xt[(k4 + 1) * ATS + j] = xv.y;
      Xt[(k4 + 2) * ATS + j] = xv.z;
      Xt[(k4 + 3) * ATS + j] = xv.w;
    }
    __syncthreads();
#pragma unroll 4
    for (int kk = 0; kk < 32; ++kk) {
      float4 y = *(const float4*)&Wt[kk * HID + f4];
      float4 a = *(const float4*)&Xt[kk * ATS + rg * 4];
      acc0.x += a.x * y.x; acc0.y += a.x * y.y; acc0.z += a.x * y.z; acc0.w += a.x * y.w;
      acc1.x += a.y * y.x; acc1.y += a.y * y.y; acc1.z += a.y * y.z; acc1.w += a.y * y.w;
      acc2.x += a.z * y.x; acc2.y += a.z * y.y; acc2.z += a.z * y.z; acc2.w += a.z * y.w;
      acc3.x += a.w * y.x; acc3.y += a.w * y.y; acc3.z += a.w * y.z; acc3.w += a.w * y.w;
    }
    __syncthreads();
  }
  int r = r0 + rg * 4;
  float4* accs[4] = {&acc0, &acc1, &acc2, &acc3};
#pragma unroll
  for (int j = 0; j < 4; ++j) {
    int row = r + j;
    if (row >= n) continue;
    float g = gate ? gate[row] : 1.0f;
    float d = dis ? dis[row] : (1.0f / sqrtf((float)(cntd[row] + selfd[row] + 2)));
    float s = d * g;
    float4 a = *accs[j];
    *(float4*)&Ysc[(size_t)row * HID + f4] = make_float4(s * a.x, s * a.y, s * a.z, s * a.w);
  }
}

// Level-0 sparse GCN + fused score (128 threads = 2 waves)
__global__ void k_gcn_sparse(const float* __restrict__ Ysc, const int* __restrict__ cnt_in,
                             const int* __restrict__ col_in, const int* __restrict__ selfc,
                             const float* __restrict__ bias, const float* __restrict__ p,
                             float* __restrict__ H, float* __restrict__ score) {
  __shared__ float red[HID];
  __shared__ float red2[HID];
  int d = blockIdx.x, f = threadIdx.x;
  int cntu = cnt_in[d];
  int cnt = cntu > CAP ? CAP : cntu;
  float acc = (2.0f + (float)selfc[d]) * Ysc[d * HID + f];
  int e = 0;
  for (; e + 8 <= cnt; e += 8) {   // ILP-8 gather, same accumulation order
    float y[8];
#pragma unroll
    for (int j = 0; j < 8; ++j) y[j] = Ysc[col_in[d * CAP + e + j] * HID + f];
#pragma unroll
    for (int j = 0; j < 8; ++j) acc += y[j];
  }
  for (; e < cnt; ++e) acc += Ysc[col_in[d * CAP + e] * HID + f];
  float d0 = 1.0f / sqrtf((float)(cntu + selfc[d] + 2));
  float h = tanhf(d0 * acc + bias[f]);
  H[d * HID + f] = h;
  float pv = p[f];
  red[f] = h * pv;
  red2[f] = pv * pv;
  __syncthreads();
  for (int s = 64; s > 0; s >>= 1) {
    if (f < s) { red[f] += red[f + s]; red2[f] += red2[f + s]; }
    __syncthreads();
  }
  if (f == 0) score[d] = tanhf(red[0] * (1.0f / sqrtf(red2[0])));
}

// Top-K, one 1024-thread block. Radix-select; the 256-bin suffix-scan is now
// wave-shuffle based (integer-exact, identical selection) -> 4 barriers/pass
// instead of 35.
__global__ __launch_bounds__(TKT) void k_topk(const float* __restrict__ score, int n, int K,
                                              int* __restrict__ perm, float* __restrict__ gatec,
                                              int* __restrict__ inv) {
  __shared__ unsigned setA[N0];
  __shared__ unsigned setB[N0];
  __shared__ int hist[256];
  __shared__ int wtot[4];
  __shared__ unsigned pfx_sh;
  __shared__ int rem_sh;
  __shared__ int cnt_sh;
  __shared__ int cgt[48], ceq[48], bgt[48], beq[48];
  int t = threadIdx.x;
  int lane = t & 63, wv = t >> 6;   // 16 waves
  unsigned long long below = (lane == 0) ? 0ull : (~0ull >> (64 - lane));
  for (int i = t; i < n; i += TKT) setA[i] = fkey(score[i]);
  __syncthreads();

  unsigned prefix = 0; int rem = K; int m = n;
  unsigned* cur = setA; unsigned* nxt = setB;
  for (int pass = 3; pass >= 0; --pass) {
    if (t < 256) hist[t] = 0;
    __syncthreads();
    for (int i = t; i < m; i += TKT) atomicAdd(&hist[(cur[i] >> (pass * 8)) & 255], 1);
    __syncthreads();
    // ---- wave-shuffle suffix scan over 256 bins (waves 0..3) ----
    int sv = 0, sh = 0;
    if (t < 256) {
      sh = hist[t];
      sv = sh;
#pragma unroll
      for (int off = 1; off < 64; off <<= 1) {
        int u = __shfl_down(sv, off);
        sv += (lane + off < 64) ? u : 0;
      }
      if (lane == 0) wtot[t >> 6] = sv;   // per-64-bin-chunk totals
    }
    __syncthreads();
    if (t < 256) {
      int w4 = t >> 6;
      int add = 0;
#pragma unroll
      for (int ww = 1; ww < 4; ++ww) {
        int idx = w4 + ww;
        if (idx < 4) add += wtot[idx];
      }
      int self_c = sv + add;                          // == old sscan[t]
      int next_c = (lane == 63) ? add : (self_c - sh); // == old sscan[t+1]
      if (self_c >= rem && next_c < rem) {
        pfx_sh = prefix | ((unsigned)t << (pass * 8));
        rem_sh = rem - next_c;
      }
    }
    __syncthreads();
    prefix = pfx_sh; rem = rem_sh;
    if (pass > 0) {
      unsigned dg = (prefix >> (pass * 8)) & 255u;
      if (t == 0) cnt_sh = 0;
      __syncthreads();
      for (int c0 = 0; c0 < m; c0 += TKT) {
        int i = c0 + t;
        unsigned u = (i < m) ? cur[i] : 0u;
        bool match = (i < m) && (((u >> (pass * 8)) & 255u) == dg);
        unsigned long long mm = __ballot(match);
        int cw = (int)__popcll(mm);
        int basew = 0;
        if (lane == 0 && cw) basew = atomicAdd(&cnt_sh, cw);
        basew = __shfl(basew, 0);
        if (match) nxt[basew + (int)__popcll(mm & below)] = u;
      }
      __syncthreads();
      m = cnt_sh;
      unsigned* tmp = cur; cur = nxt; nxt = tmp;
    }
  }
  unsigned uthr = prefix;
  int c_gt = K - rem;
  int NC = (n + 63) >> 6;           // <= 47 chunks of 64
  for (int c = wv; c < NC; c += 16) {
    int i = (c << 6) + lane;
    unsigned u = (i < n) ? fkey(score[i]) : 0u;
    bool isgt = (i < n) && (u > uthr);
    bool iseq = (i < n) && (u == uthr);
    unsigned long long mg = __ballot(isgt);
    unsigned long long me = __ballot(iseq);
    if (lane == 0) { cgt[c] = (int)__popcll(mg); ceq[c] = (int)__popcll(me); }
  }
  __syncthreads();
  if (t == 0) {
    int g = 0, e = 0;
    for (int c = 0; c < NC; ++c) { bgt[c] = g; g += cgt[c]; beq[c] = e; e += ceq[c]; }
  }
  __syncthreads();
  for (int c = wv; c < NC; c += 16) {
    int i = (c << 6) + lane;
    unsigned u = (i < n) ? fkey(score[i]) : 0u;
    bool isgt = (i < n) && (u > uthr);
    bool iseq = (i < n) && (u == uthr);
    unsigned long long mg = __ballot(isgt);
    unsigned long long me = __ballot(iseq);
    if (isgt) {
      int pos = bgt[c] + (int)__popcll(mg & below);
      perm[pos] = i; gatec[pos] = inv_fkey(u); inv[i] = pos;
    } else if (iseq) {
      int er = beq[c] + (int)__popcll(me & below);
      if (er < rem) { int pos = c_gt + er; perm[pos] = i; gatec[pos] = inv_fkey(u); inv[i] = pos; }
    }
  }
}

// Row-wise A1 build -> CSR + dis1 (dense A1 write retired).
__global__ __launch_bounds__(256) void k_rowcsr(const int* __restrict__ perm1,
                                                const int* __restrict__ inv1,
                                                const int* __restrict__ cnt_in,
                                                const int* __restrict__ col_in,
                                                int* __restrict__ csr_n,
                                                int* __restrict__ csr_k,
                                                float* __restrict__ csr_w,
                                                float* __restrict__ dis1) {
  __shared__ int row[K1N];
  __shared__ int cntw[4];
  __shared__ int wsum_sh;
  int r = blockIdx.x, t = threadIdx.x;
  for (int i = t; i < K1N; i += 256) row[i] = 0;
  if (t == 0) wsum_sh = 0;
  __syncthreads();
  int d = perm1[r];
  int ni = cnt_in[d]; if (ni > CAP) ni = CAP;
  // +2*A' term (col_in excludes self-loops)
  if (t < ni) {
    int s = col_in[d * CAP + t];
    int jj = inv1[s];
    if (jj >= 0) atomicAdd(&row[jj], 2);
  }
  // middle term: a over in-edges of d (32 lanes), b over in-edges of m (8 lanes)
  {
    int ta = t >> 3, tb = t & 7;
    for (int a = ta; a < ni; a += 32) {
      int m = col_in[d * CAP + a];
      int nm = cnt_in[m]; if (nm > CAP) nm = CAP;
      for (int b = tb; b < nm; b += 8) {
        int s = col_in[m * CAP + b];
        if (s != d) {
          int jj = inv1[s];
          if (jj >= 0) atomicAdd(&row[jj], 1);
        }
      }
    }
  }
  __syncthreads();
  // compact to CSR (ascending cols) + int-exact rowsum
  int wid = t >> 6, lane = t & 63;
  unsigned long long below = (lane == 0) ? 0ull : (~0ull >> (64 - lane));
  int base = 0, ws = 0;
  int* gk = csr_k + (size_t)r * RCAP;
  float* gw = csr_w + (size_t)r * RCAP;
  for (int c0 = 0; c0 < K1N; c0 += 256) {
    int col = c0 + t;
    int v = (col < K1N) ? row[col] : 0;
    ws += v;
    bool nz = (v != 0);
    unsigned long long m = __ballot(nz);
    if (lane == 0) cntw[wid] = (int)__popcll(m);
    __syncthreads();
    int pref = 0;
#pragma unroll
    for (int w = 0; w < 4; ++w) if (w < wid) pref += cntw[w];
    int pos = base + pref + (int)__popcll(m & below);
    if (nz) { gk[pos] = col; gw[pos] = (float)v; }
    base += cntw[0] + cntw[1] + cntw[2] + cntw[3];
    __syncthreads();
  }
  for (int off = 32; off > 0; off >>= 1) ws += __shfl_down(ws, off);
  if (lane == 0) atomicAdd(&wsum_sh, ws);
  __syncthreads();
  if (t == 0) {
    csr_n[r] = base;
    dis1[r] = 1.0f / sqrtf((float)wsum_sh + 2.0f);
  }
}

// Ac scatter-build from CSR: Ac[k][inv2[col]] = (short)w  (zeros elsewhere).
// Identical values to the old dense gather (A1 entries are small ints).
__global__ __launch_bounds__(256) void k_cmp(const int* __restrict__ csr_n,
                                             const int* __restrict__ csr_k,
                                             const float* __restrict__ csr_w,
                                             const int* __restrict__ inv2,
                                             short* __restrict__ Ac) {
  int k = blockIdx.x, t = threadIdx.x;
  short* dst = Ac + (size_t)k * LD2;
  for (int i = t; i < LD2; i += 256) dst[i] = 0;
  __syncthreads();
  int nnz = csr_n[k];
  const int* gk = csr_k + (size_t)k * RCAP;
  const float* gw = csr_w + (size_t)k * RCAP;
  for (int i = t; i < nnz; i += 256) {
    int c = inv2[gk[i]];
    if (c >= 0) dst[c] = (short)gw[i];
  }
}

// A2[a][b] = (b!=a) ? sum_k A1[qa][k]*Ac[k][b] + 2*Ac[qa][b] : 0
// 192 threads (all active); LDS-staged CSR row; int16 Ac, ILP-8; fused dis2.
__global__ __launch_bounds__(192) void k_sq2(const short* __restrict__ Ac,
                                             const int* __restrict__ perm2,
                                             const int* __restrict__ csr_n,
                                             const int* __restrict__ csr_k,
                                             const float* __restrict__ csr_w,
                                             float* __restrict__ A2,
                                             float* __restrict__ dis2) {
  __shared__ int klist[K1N];
  __shared__ float wlist[K1N];
  __shared__ float wred[3];
  int a = blockIdx.x, t = threadIdx.x;
  int qa = perm2[a];
  if (qa < 0) qa = 0;
  if (qa >= K1N) qa = K1N - 1;
  const short* acq = Ac + (size_t)qa * LD2;
  int nnz = csr_n[qa];
  {
    const int* gk = csr_k + (size_t)qa * RCAP;
    const float* gw = csr_w + (size_t)qa * RCAP;
    for (int c = t; c < nnz; c += 192) { klist[c] = gk[c]; wlist[c] = gw[c]; }
  }
  __syncthreads();
  int c0 = t * 4;                     // 0..764, always in-range
  float4 acc = make_float4(0.f, 0.f, 0.f, 0.f);
  int p = 0;
  for (; p + 8 <= nnz; p += 8) {      // 8 independent L2 loads in flight
    int kk[8]; float ww[8];
#pragma unroll
    for (int j = 0; j < 8; ++j) { kk[j] = klist[p + j]; ww[j] = wlist[p + j]; }
    short4 v[8];
#pragma unroll
    for (int j = 0; j < 8; ++j) v[j] = *(const short4*)&Ac[(size_t)kk[j] * LD2 + c0];
#pragma unroll
    for (int j = 0; j < 8; ++j) {
      acc.x += ww[j] * (float)v[j].x;
      acc.y += ww[j] * (float)v[j].y;
      acc.z += ww[j] * (float)v[j].z;
      acc.w += ww[j] * (float)v[j].w;
    }
  }
  for (; p < nnz; ++p) {
    int k = klist[p]; float w = wlist[p];
    short4 v = *(const short4*)&Ac[(size_t)k * LD2 + c0];
    acc.x += w * (float)v.x; acc.y += w * (float)v.y;
    acc.z += w * (float)v.z; acc.w += w * (float)v.w;
  }
  float rsum = 0.0f;
  {
    float accv[4] = {acc.x, acc.y, acc.z, acc.w};
    float outv[4];
#pragma unroll
    for (int j = 0; j < 4; ++j) {
      int col = c0 + j;
      float v = 0.0f;
      if (col < K2N && col != a) {
        v = accv[j] + 2.0f * (float)acq[col];
      }
      outv[j] = v;
      rsum += v;
    }
    *(float4*)&A2[(size_t)a * LD2 + c0] = make_float4(outv[0], outv[1], outv[2], outv[3]);
  }
  for (int off = 32; off > 0; off >>= 1) rsum += __shfl_down(rsum, off);
  if ((t & 63) == 0) wred[t >> 6] = rsum;
  __syncthreads();
  if (t == 0) dis2[a] = 1.0f / sqrtf(wred[0] + wred[1] + wred[2] + 2.0f);
}

// CSR-based row-sparse GCN aggregation + epilogue (+ optional fused score).
__global__ __launch_bounds__(128) void k_spmv_csr(const int* __restrict__ csr_n,
                                                  const int* __restrict__ csr_k,
                                                  const float* __restrict__ csr_w,
                                                  const float* __restrict__ Ysc,
                                                  const float* __restrict__ dis,
                                                  const float* __restrict__ bias,
                                                  const float* __restrict__ p,
                                                  float* __restrict__ H,
                                                  float* __restrict__ score, int act) {
  __shared__ int klist[K1N];
  __shared__ float wlist[K1N];
  __shared__ float red[HID];
  __shared__ float red2[HID];
  int r = blockIdx.x, t = threadIdx.x;
  int nnz = csr_n[r];
  {
    const int* gk = csr_k + (size_t)r * RCAP;
    const float* gw = csr_w + (size_t)r * RCAP;
    for (int i = t; i < nnz; i += 128) { klist[i] = gk[i]; wlist[i] = gw[i]; }
  }
  __syncthreads();
  float acc = 0.0f;
  int pp = 0;
  for (; pp + 8 <= nnz; pp += 8) {
    float y[8];
#pragma unroll
    for (int j = 0; j < 8; ++j) y[j] = Ysc[(size_t)klist[pp + j] * HID + t];
#pragma unroll
    for (int j = 0; j < 8; ++j) acc += wlist[pp + j] * y[j];
  }
  for (; pp < nnz; ++pp) acc += wlist[pp] * Ysc[(size_t)klist[pp] * HID + t];
  float zv = dis[r] * (acc + 2.0f * Ysc[(size_t)r * HID + t]) + bias[t];
  float h = act ? tanhf(zv) : zv;
  H[(size_t)r * HID + t] = h;
  if (p) {
    float pv = p[t];
    red[t] = h * pv;
    red2[t] = pv * pv;
    __syncthreads();
    for (int s = 64; s > 0; s >>= 1) {
      if (t < s) { red[t] += red[t + s]; red2[t] += red2[t + s]; }
      __syncthreads();
    }
    if (t == 0) score[r] = tanhf(red[0] * (1.0f / sqrtf(red2[0])));
  }
}

// Dense direct spmv for A2: all cols ascending (bit-exact vs compacted scan).
__global__ __launch_bounds__(128) void k_spmv2(const float* __restrict__ A2,
                                               const float* __restrict__ Ysc,
                                               const float* __restrict__ dis2,
                                               const float* __restrict__ bias,
                                               float* __restrict__ H) {
  int r = blockIdx.x, t = threadIdx.x;
  const float* arow = A2 + (size_t)r * LD2;
  float acc = 0.0f;
  int c = 0;
  for (; c + 8 <= K2N; c += 8) {
    float w[8], y[8];
#pragma unroll
    for (int j = 0; j < 8; ++j) w[j] = arow[c + j];
#pragma unroll
    for (int j = 0; j < 8; ++j) y[j] = Ysc[(size_t)(c + j) * HID + t];
#pragma unroll
    for (int j = 0; j < 8; ++j) acc += w[j] * y[j];
  }
  for (; c < K2N; ++c) acc += arow[c] * Ysc[(size_t)c * HID + t];
  float zv = dis2[r] * (acc + 2.0f * Ysc[(size_t)r * HID + t]) + bias[t];
  H[(size_t)r * HID + t] = tanhf(zv);
}

// Yfsc[i] = dis0[i] * ((h0[i] + scatter(u1b)) @ W_up1)   [N0 x 3]
__global__ void k_yf(const float* __restrict__ h0, const float* __restrict__ u1b,
                     const int* __restrict__ inv1, const float* __restrict__ Wup1,
                     const int* __restrict__ cnt_in, const int* __restrict__ selfc,
                     float* __restrict__ Yfsc) {
  __shared__ float red[3][HID];
  int i = blockIdx.x, t = threadIdx.x;
  float v = h0[i * HID + t];
  int ii = inv1[i];
  if (ii >= 0 && ii < K1N) v += u1b[ii * HID + t];
#pragma unroll
  for (int c = 0; c < 3; ++c) red[c][t] = v * Wup1[t * 3 + c];
  __syncthreads();
  for (int s = 64; s > 0; s >>= 1) {
    if (t < s) { red[0][t] += red[0][t + s]; red[1][t] += red[1][t + s]; red[2][t] += red[2][t + s]; }
    __syncthreads();
  }
  if (t < 3) {
    float d0 = 1.0f / sqrtf((float)(cnt_in[i] + selfc[i] + 2));
    Yfsc[i * 3 + t] = d0 * red[t][0];
  }
}

__global__ void k_final(const float* __restrict__ Yfsc, const int* __restrict__ cnt_in,
                        const int* __restrict__ col_in, const int* __restrict__ selfc,
                        const float* __restrict__ bup1, const float* __restrict__ z,
                        float* __restrict__ out) {
  int idx = blockIdx.x * blockDim.x + threadIdx.x;
  if (idx >= N0 * 3) return;
  int d = idx / 3, c = idx - d * 3;
  int cntu = cnt_in[d];
  int cnt = cntu > CAP ? CAP : cntu;
  float acc = (2.0f + (float)selfc[d]) * Yfsc[d * 3 + c];
  int e = 0;
  for (; e + 8 <= cnt; e += 8) {   // ILP-8 gather, same accumulation order
    float y[8];
#pragma unroll
    for (int j = 0; j < 8; ++j) y[j] = Yfsc[col_in[d * CAP + e + j] * 3 + c];
#pragma unroll
    for (int j = 0; j < 8; ++j) acc += y[j];
  }
  for (; e < cnt; ++e) acc += Yfsc[col_in[d * CAP + e] * 3 + c];
  float d0 = 1.0f / sqrtf((float)(cntu + selfc[d] + 2));
  out[idx] = d0 * acc + bup1[c] + 0.1f * z[idx];
}

extern "C" void kernel_launch(void* const* d_in, const int* in_sizes, int n_in,
                              void* d_out, int out_size, void* d_ws, size_t ws_size,
                              hipStream_t stream) {
  const float* x   = (const float*)d_in[0];
  const float* z   = (const float*)d_in[1];
  const float* Wd0 = (const float*)d_in[2];
  const float* bd0 = (const float*)d_in[3];
  const float* Wd1 = (const float*)d_in[4];
  const float* bd1 = (const float*)d_in[5];
  const float* Wd2 = (const float*)d_in[6];
  const float* bd2 = (const float*)d_in[7];
  const float* p1  = (const float*)d_in[8];
  const float* p2  = (const float*)d_in[9];
  const float* Wu0 = (const float*)d_in[10];
  const float* bu0 = (const float*)d_in[11];
  const float* Wu1 = (const float*)d_in[12];
  const float* bu1 = (const float*)d_in[13];
  const int*   ei  = (const int*)d_in[14];

  if (ws_size < F_END * sizeof(float)) return;

  float* W     = (float*)d_ws;
  short* Ac    = (short*)(W + F_SCR);
  float* A2    = W + F_A2;
  float* Ysc   = W + F_YSC;
  float* h0    = W + F_H0;
  float* h1    = W + F_H1;
  float* h2    = W + F_H2;
  float* u1b   = W + F_U1B;
  float* Yfsc  = W + F_YF;
  float* score = W + F_SCORE;
  float* gate1 = W + F_GATE1;
  float* gate2 = W + F_GATE2;
  float* dis1  = W + F_DIS1;
  float* dis2  = W + F_DIS2;
  int* perm1   = (int*)(W + F_PERM1);
  int* perm2   = (int*)(W + F_PERM2);
  int* inv1    = (int*)(W + F_INV1);
  int* inv2    = (int*)(W + F_INV2);
  int* cnt_in  = (int*)(W + F_CNTI);
  int* selfc   = (int*)(W + F_SELF);
  int* col_in  = (int*)(W + F_CI);
  int* csr_n   = (int*)(W + F_CSRN);
  int* csr_k   = (int*)(W + F_CSRK);
  float* csr_w = W + F_CSRW;
  float* out   = (float*)d_out;

  // ---- init ----
  k_init<<<128, 256, 0, stream>>>(gate1, perm1, inv1, cnt_in, out + N0 * 3);

  // ---- in-edge lists ----
  k_count<<<(E0 + 255) / 256, 256, 0, stream>>>(ei, cnt_in, selfc, col_in);

  // ---- level 0 GCN + pool-1 score ----
  k_yw2<<<(N0 + BM - 1) / BM, 256, 0, stream>>>(x, nullptr, nullptr, 32, N0, N0, Wd0,
                                                nullptr, nullptr, nullptr, cnt_in, selfc, Ysc);
  k_gcn_sparse<<<N0, HID, 0, stream>>>(Ysc, cnt_in, col_in, selfc, bd0, p1, h0, score);
  k_topk<<<1, TKT, 0, stream>>>(score, N0, K1N, perm1, gate1, inv1);

  // ---- A1 rows: build + CSR + dis1 (dense A1 retired) ----
  k_rowcsr<<<K1N, 256, 0, stream>>>(perm1, inv1, cnt_in, col_in, csr_n, csr_k, csr_w, dis1);

  // ---- level 1 GCN (CSR spmv) + pool-2 score fused ----
  k_yw2<<<(K1N + BM - 1) / BM, 256, 0, stream>>>(h0, nullptr, nullptr, HID, N0, K1N, Wd1,
                                                 perm1, gate1, dis1, nullptr, nullptr, Ysc);
  k_spmv_csr<<<K1N, 128, 0, stream>>>(csr_n, csr_k, csr_w, Ysc, dis1, bd1, p2, h1, score, 1);
  k_topk<<<1, TKT, 0, stream>>>(score, K1N, K2N, perm2, gate2, inv2);

  // ---- A2 = augment(A1)[perm2][:,perm2] (Ac scatter-build + int16 matmul + dis2) ----
  k_cmp<<<K1N, 256, 0, stream>>>(csr_n, csr_k, csr_w, inv2, Ac);
  k_sq2<<<K2N, 192, 0, stream>>>(Ac, perm2, csr_n, csr_k, csr_w, A2, dis2);

  // ---- level 2 GCN (dense direct spmv on A2) ----
  k_yw2<<<(K2N + BM - 1) / BM, 256, 0, stream>>>(h1, nullptr, nullptr, HID, K1N, K2N, Wd2,
                                                 perm2, gate2, dis2, nullptr, nullptr, Ysc);
  k_spmv2<<<K2N, 128, 0, stream>>>(A2, Ysc, dis2, bd2, h2);

  // ---- up path (combine fused into staging; CSR spmv) ----
  k_yw2<<<(K1N + BM - 1) / BM, 256, 0, stream>>>(h1, h2, inv2, HID, K1N, K1N, Wu0,
                                                 nullptr, nullptr, dis1, nullptr, nullptr, Ysc);
  k_spmv_csr<<<K1N, 128, 0, stream>>>(csr_n, csr_k, csr_w, Ysc, dis1, bu0, nullptr, u1b, nullptr, 1);

  // ---- final ----
  k_yf<<<N0, HID, 0, stream>>>(h0, u1b, inv1, Wu1, cnt_in, selfc, Yfsc);
  k_final<<<(N0 * 3 + 255) / 256, 256, 0, stream>>>(Yfsc, cnt_in, col_in, selfc, bu1, z, out);
}

// Round 6
// 234.208 us; speedup vs baseline: 1.1847x; 1.0374x over previous
//
#include <hip/hip_runtime.h>
#include <hip/hip_bf16.h>

#define N0   3000
#define E0   48000
#define K1N  1500
#define K2N  750
#define HID  128
#define CAP  128
#define LD1  1536  // (A1 dense retired; offset kept for layout compat)
#define LD2  768   // padded leading dim for A2/Ac
#define BM   32    // row-tile for yw2
#define ATS  36    // transposed X-tile stride (BM+4, bank-spread)
#define RCAP 1536  // CSR row capacity (>= max possible nnz = K1N)
#define TKT  1024  // k_topk threads (16 waves on one CU)
#define NBC  188   // edge blocks in k_cntyw ((E0+255)/256)
#define NBY0 94    // yw2 L0 blocks ((N0+BM-1)/BM)
#define NBY1 47    // yw2 L1/up blocks ((K1N+BM-1)/BM)
#define NBY2 24    // yw2 L2 blocks ((K2N+BM-1)/BM)

__device__ __forceinline__ unsigned fkey(float f) {
  unsigned u = __float_as_uint(f);
  return (u & 0x80000000u) ? ~u : (u | 0x80000000u);
}
__device__ __forceinline__ float inv_fkey(unsigned u) {
  unsigned v = (u & 0x80000000u) ? (u & 0x7FFFFFFFu) : ~u;
  return __uint_as_float(v);
}

// ---------------- workspace layout (float units) ----------------
constexpr size_t F_A1    = 0;                          // retired (hole)
constexpr size_t F_SCR   = F_A1 + (size_t)K1N * LD1;   // Ac (int16) = K1N*LD2 shorts
constexpr size_t SCR_SZ  = 1155072;
constexpr size_t F_A2    = F_SCR + SCR_SZ;             // K2N*LD2
constexpr size_t F_YSC   = F_A2 + (size_t)K2N * LD2;   // N0*HID
constexpr size_t F_H0    = F_YSC + (size_t)N0 * HID;   // N0*HID
constexpr size_t F_H1    = F_H0 + (size_t)N0 * HID;    // K1N*HID
constexpr size_t F_H2    = F_H1 + (size_t)K1N * HID;   // K2N*HID
constexpr size_t F_U1    = F_H2 + (size_t)K2N * HID;   // (hole)
constexpr size_t F_U1B   = F_U1 + (size_t)K1N * HID;   // (hole, u1b retired)
constexpr size_t F_YF    = F_U1B + (size_t)K1N * HID;  // N0*3
constexpr size_t F_SCORE = F_YF + (size_t)N0 * 3;      // N0
constexpr size_t F_GATE1 = F_SCORE + N0;               // K1N
constexpr size_t F_GATE2 = F_GATE1 + K1N;              // K2N
constexpr size_t F_DIS0  = F_GATE2 + K2N;              // (unused)
constexpr size_t F_DIS1  = F_DIS0 + N0;                // K1N
constexpr size_t F_DIS2  = F_DIS1 + K1N;               // K2N
constexpr size_t F_PERM1 = F_DIS2 + K2N;               // K1N (int)
constexpr size_t F_PERM2 = F_PERM1 + K1N;              // K2N (int)
constexpr size_t F_INV1  = F_PERM2 + K2N;              // N0  (int)
constexpr size_t F_INV2  = F_INV1 + N0;                // K1N (int)
constexpr size_t F_CNTI  = F_INV2 + K1N;               // N0  (int)
constexpr size_t F_CNTO  = F_CNTI + N0;                // N0  (int) (unused)
constexpr size_t F_SELF  = F_CNTO + N0;                // N0  (int)
constexpr size_t F_CI    = F_SELF + N0;                // N0*CAP (int)
constexpr size_t F_CO    = F_CI + (size_t)N0 * CAP;    // N0*CAP (int) (unused)
constexpr size_t F_CSRN  = F_CO + (size_t)N0 * CAP;    // K1N (int)
constexpr size_t F_CSRK  = F_CSRN + K1N;               // K1N*RCAP (int)
constexpr size_t F_CSRW  = F_CSRK + (size_t)K1N * RCAP;// K1N*RCAP (float)
constexpr size_t F_END   = F_CSRW + (size_t)K1N * RCAP;

// ---------------- init (fills) ----------------
__global__ void k_init(float* __restrict__ gate, int* __restrict__ perm,
                       int* __restrict__ inv, int* __restrict__ cnt,
                       float* __restrict__ outlab) {
  int i = blockIdx.x * blockDim.x + threadIdx.x, st = gridDim.x * blockDim.x;
  for (int j = i; j < K1N + K2N; j += st) gate[j] = 0.0f;
  for (int j = i; j < K1N + K2N; j += st) perm[j] = 0;
  for (int j = i; j < N0 + K1N; j += st) inv[j] = -1;
  for (int j = i; j < 3 * N0; j += st) cnt[j] = 0;
  for (int j = i; j < N0 * 29; j += st) outlab[j] = 0.0f;
}

// ---------------- shared yw2 tile body (UNSCALED output) [R4-verified] ----------------
struct __align__(16) YWShared { float Wt[32 * HID]; float Xt[32 * ATS]; };

__device__ __forceinline__ void yw2_body(YWShared* sm, int bid,
                                         const float* __restrict__ X,
                                         const float* __restrict__ X2,
                                         const int* __restrict__ inv2c,
                                         int Kin, int nsrc, int n,
                                         const float* __restrict__ Wm,
                                         const int* __restrict__ perm,
                                         float* __restrict__ Ysc) {
  int t = threadIdx.x;
  int r0 = bid * BM;
  int f4 = (t & 31) * 4;
  int rg = t >> 5;
  float4 acc0 = {0,0,0,0}, acc1 = {0,0,0,0}, acc2 = {0,0,0,0}, acc3 = {0,0,0,0};
  for (int kb = 0; kb < Kin; kb += 32) {
    {
      const float4* src = (const float4*)(Wm + (size_t)kb * HID);
      float4* dst = (float4*)sm->Wt;
#pragma unroll
      for (int i = 0; i < 4; ++i) dst[i * 256 + t] = src[i * 256 + t];
    }
    {
      int j = t >> 3;
      int k4 = (t & 7) * 4;
      int r = r0 + j;
      int src_row = (r < n) ? r : (n - 1);
      if (perm) {
        int s = perm[src_row];
        if (s < 0) s = 0;
        if (s >= nsrc) s = nsrc - 1;
        src_row = s;
      }
      float4 xv = *(const float4*)(X + (size_t)src_row * Kin + kb + k4);
      if (X2) {
        int ii = inv2c[src_row];
        if (ii >= 0 && ii < K2N) {
          float4 x2 = *(const float4*)(X2 + (size_t)ii * Kin + kb + k4);
          xv.x += x2.x; xv.y += x2.y; xv.z += x2.z; xv.w += x2.w;
        }
      }
      sm->Xt[(k4 + 0) * ATS + j] = xv.x;
      sm->Xt[(k4 + 1) * ATS + j] = xv.y;
      sm->Xt[(k4 + 2) * ATS + j] = xv.z;
      sm->Xt[(k4 + 3) * ATS + j] = xv.w;
    }
    __syncthreads();
#pragma unroll 4
    for (int kk = 0; kk < 32; ++kk) {
      float4 y = *(const float4*)&sm->Wt[kk * HID + f4];
      float4 a = *(const float4*)&sm->Xt[kk * ATS + rg * 4];
      acc0.x += a.x * y.x; acc0.y += a.x * y.y; acc0.z += a.x * y.z; acc0.w += a.x * y.w;
      acc1.x += a.y * y.x; acc1.y += a.y * y.y; acc1.z += a.y * y.z; acc1.w += a.y * y.w;
      acc2.x += a.z * y.x; acc2.y += a.z * y.y; acc2.z += a.z * y.z; acc2.w += a.z * y.w;
      acc3.x += a.w * y.x; acc3.y += a.w * y.y; acc3.z += a.w * y.z; acc3.w += a.w * y.w;
    }
    __syncthreads();
  }
  int r = r0 + rg * 4;
  float4* accs[4] = {&acc0, &acc1, &acc2, &acc3};
#pragma unroll
  for (int j = 0; j < 4; ++j) {
    int row = r + j;
    if (row >= n) continue;
    *(float4*)&Ysc[(size_t)row * HID + f4] = *accs[j];
  }
}

// ---------------- scaled yw2 (producer-side dis/gate) [R5-verified] ----------------
__global__ __launch_bounds__(256) void k_yw2(const float* __restrict__ X,
                                             const float* __restrict__ X2,
                                             const int* __restrict__ inv2c,
                                             int Kin, int nsrc, int n,
                                             const float* __restrict__ Wm,
                                             const int* __restrict__ perm,
                                             const float* __restrict__ gate,
                                             const float* __restrict__ dis,
                                             float* __restrict__ Ysc) {
  __shared__ float Wt[32 * HID];
  __shared__ float Xt[32 * ATS];
  int t = threadIdx.x;
  int r0 = blockIdx.x * BM;
  int f4 = (t & 31) * 4;
  int rg = t >> 5;
  float4 acc0 = {0,0,0,0}, acc1 = {0,0,0,0}, acc2 = {0,0,0,0}, acc3 = {0,0,0,0};
  for (int kb = 0; kb < Kin; kb += 32) {
    {
      const float4* src = (const float4*)(Wm + (size_t)kb * HID);
      float4* dst = (float4*)Wt;
#pragma unroll
      for (int i = 0; i < 4; ++i) dst[i * 256 + t] = src[i * 256 + t];
    }
    {
      int j = t >> 3;
      int k4 = (t & 7) * 4;
      int r = r0 + j;
      int src_row = (r < n) ? r : (n - 1);
      if (perm) {
        int s = perm[src_row];
        if (s < 0) s = 0;
        if (s >= nsrc) s = nsrc - 1;
        src_row = s;
      }
      float4 xv = *(const float4*)(X + (size_t)src_row * Kin + kb + k4);
      if (X2) {
        int ii = inv2c[src_row];
        if (ii >= 0 && ii < K2N) {
          float4 x2 = *(const float4*)(X2 + (size_t)ii * Kin + kb + k4);
          xv.x += x2.x; xv.y += x2.y; xv.z += x2.z; xv.w += x2.w;
        }
      }
      Xt[(k4 + 0) * ATS + j] = xv.x;
      Xt[(k4 + 1) * ATS + j] = xv.y;
      Xt[(k4 + 2) * ATS + j] = xv.z;
      Xt[(k4 + 3) * ATS + j] = xv.w;
    }
    __syncthreads();
#pragma unroll 4
    for (int kk = 0; kk < 32; ++kk) {
      float4 y = *(const float4*)&Wt[kk * HID + f4];
      float4 a = *(const float4*)&Xt[kk * ATS + rg * 4];
      acc0.x += a.x * y.x; acc0.y += a.x * y.y; acc0.z += a.x * y.z; acc0.w += a.x * y.w;
      acc1.x += a.y * y.x; acc1.y += a.y * y.y; acc1.z += a.y * y.z; acc1.w += a.y * y.w;
      acc2.x += a.z * y.x; acc2.y += a.z * y.y; acc2.z += a.z * y.z; acc2.w += a.z * y.w;
      acc3.x += a.w * y.x; acc3.y += a.w * y.y; acc3.z += a.w * y.z; acc3.w += a.w * y.w;
    }
    __syncthreads();
  }
  int r = r0 + rg * 4;
  float4* accs[4] = {&acc0, &acc1, &acc2, &acc3};
#pragma unroll
  for (int j = 0; j < 4; ++j) {
    int row = r + j;
    if (row >= n) continue;
    float g = gate ? gate[row] : 1.0f;
    float s = dis[row] * g;
    float4 a = *accs[j];
    *(float4*)&Ysc[(size_t)row * HID + f4] = make_float4(s * a.x, s * a.y, s * a.z, s * a.w);
  }
}

// ---------------- edge count || yw2-L0 (merged) [R4-verified] ----------------
__global__ __launch_bounds__(256) void k_cntyw(const int* __restrict__ ei,
                                               int* cnt_in, int* selfc, int* col_in,
                                               const float* __restrict__ x,
                                               const float* __restrict__ Wd0,
                                               float* __restrict__ Ysc) {
  __shared__ YWShared smy;
  int b = blockIdx.x;
  if (b < NBC) {
    int e = b * 256 + threadIdx.x;
    if (e < E0) {
      int s = ei[e], d = ei[E0 + e];
      if (s == d) { atomicAdd(&selfc[d], 1); }
      else {
        int a = atomicAdd(&cnt_in[d], 1);
        if (a < CAP) col_in[d * CAP + a] = s;
      }
    }
    return;
  }
  yw2_body(&smy, b - NBC, x, nullptr, nullptr, 32, N0, N0, Wd0, nullptr, Ysc);
}

// ---------------- level-0 sparse GCN + score (col scale at dst) [R4-verified] --------
__global__ void k_gcn_sparse(const float* __restrict__ Yraw, const int* __restrict__ cnt_in,
                             const int* __restrict__ col_in, const int* __restrict__ selfc,
                             const float* __restrict__ bias, const float* __restrict__ p,
                             float* __restrict__ H, float* __restrict__ score) {
  __shared__ float red[HID];
  __shared__ float red2[HID];
  int d = blockIdx.x, f = threadIdx.x;
  int cntu = cnt_in[d];
  int cnt = cntu > CAP ? CAP : cntu;
  int scd = selfc[d];
  float d0d = 1.0f / sqrtf((float)(cntu + scd + 2));
  float yd = d0d * Yraw[(size_t)d * HID + f];
  float acc = (2.0f + (float)scd) * yd;
  int e = 0;
  for (; e + 8 <= cnt; e += 8) {
    int cols[8];
#pragma unroll
    for (int j = 0; j < 8; ++j) cols[j] = col_in[d * CAP + e + j];
    float s[8];
#pragma unroll
    for (int j = 0; j < 8; ++j)
      s[j] = 1.0f / sqrtf((float)(cnt_in[cols[j]] + selfc[cols[j]] + 2));
    float y[8];
#pragma unroll
    for (int j = 0; j < 8; ++j) y[j] = s[j] * Yraw[(size_t)cols[j] * HID + f];
#pragma unroll
    for (int j = 0; j < 8; ++j) acc += y[j];
  }
  for (; e < cnt; ++e) {
    int c = col_in[d * CAP + e];
    float s = 1.0f / sqrtf((float)(cnt_in[c] + selfc[c] + 2));
    acc += s * Yraw[(size_t)c * HID + f];
  }
  float h = tanhf(d0d * acc + bias[f]);
  H[(size_t)d * HID + f] = h;
  float pv = p[f];
  red[f] = h * pv;
  red2[f] = pv * pv;
  __syncthreads();
  for (int s = 64; s > 0; s >>= 1) {
    if (f < s) { red[f] += red[f + s]; red2[f] += red2[f + s]; }
    __syncthreads();
  }
  if (f == 0) score[d] = tanhf(red[0] * (1.0f / sqrtf(red2[0])));
}

// ---------------- top-K (R5-verified, wave-shuffle scan) ----------------
__global__ __launch_bounds__(TKT) void k_topk(const float* __restrict__ score, int n, int K,
                                              int* __restrict__ perm, float* __restrict__ gatec,
                                              int* __restrict__ inv) {
  __shared__ unsigned setA[N0];
  __shared__ unsigned setB[N0];
  __shared__ int hist[256];
  __shared__ int wtot[4];
  __shared__ unsigned pfx_sh;
  __shared__ int rem_sh;
  __shared__ int cnt_sh;
  __shared__ int cgt[48], ceq[48], bgt[48], beq[48];
  int t = threadIdx.x;
  int lane = t & 63, wv = t >> 6;
  unsigned long long below = (lane == 0) ? 0ull : (~0ull >> (64 - lane));
  for (int i = t; i < n; i += TKT) setA[i] = fkey(score[i]);
  __syncthreads();

  unsigned prefix = 0; int rem = K; int m = n;
  unsigned* cur = setA; unsigned* nxt = setB;
  for (int pass = 3; pass >= 0; --pass) {
    if (t < 256) hist[t] = 0;
    __syncthreads();
    for (int i = t; i < m; i += TKT) atomicAdd(&hist[(cur[i] >> (pass * 8)) & 255], 1);
    __syncthreads();
    int sv = 0, sh = 0;
    if (t < 256) {
      sh = hist[t];
      sv = sh;
#pragma unroll
      for (int off = 1; off < 64; off <<= 1) {
        int u = __shfl_down(sv, off);
        sv += (lane + off < 64) ? u : 0;
      }
      if (lane == 0) wtot[t >> 6] = sv;
    }
    __syncthreads();
    if (t < 256) {
      int w4 = t >> 6;
      int add = 0;
#pragma unroll
      for (int ww = 1; ww < 4; ++ww) {
        int idx = w4 + ww;
        if (idx < 4) add += wtot[idx];
      }
      int self_c = sv + add;
      int next_c = (lane == 63) ? add : (self_c - sh);
      if (self_c >= rem && next_c < rem) {
        pfx_sh = prefix | ((unsigned)t << (pass * 8));
        rem_sh = rem - next_c;
      }
    }
    __syncthreads();
    prefix = pfx_sh; rem = rem_sh;
    if (pass > 0) {
      unsigned dg = (prefix >> (pass * 8)) & 255u;
      if (t == 0) cnt_sh = 0;
      __syncthreads();
      for (int c0 = 0; c0 < m; c0 += TKT) {
        int i = c0 + t;
        unsigned u = (i < m) ? cur[i] : 0u;
        bool match = (i < m) && (((u >> (pass * 8)) & 255u) == dg);
        unsigned long long mm = __ballot(match);
        int cw = (int)__popcll(mm);
        int basew = 0;
        if (lane == 0 && cw) basew = atomicAdd(&cnt_sh, cw);
        basew = __shfl(basew, 0);
        if (match) nxt[basew + (int)__popcll(mm & below)] = u;
      }
      __syncthreads();
      m = cnt_sh;
      unsigned* tmp = cur; cur = nxt; nxt = tmp;
    }
  }
  unsigned uthr = prefix;
  int c_gt = K - rem;
  int NC = (n + 63) >> 6;
  for (int c = wv; c < NC; c += 16) {
    int i = (c << 6) + lane;
    unsigned u = (i < n) ? fkey(score[i]) : 0u;
    bool isgt = (i < n) && (u > uthr);
    bool iseq = (i < n) && (u == uthr);
    unsigned long long mg = __ballot(isgt);
    unsigned long long me = __ballot(iseq);
    if (lane == 0) { cgt[c] = (int)__popcll(mg); ceq[c] = (int)__popcll(me); }
  }
  __syncthreads();
  if (t == 0) {
    int g = 0, e = 0;
    for (int c = 0; c < NC; ++c) { bgt[c] = g; g += cgt[c]; beq[c] = e; e += ceq[c]; }
  }
  __syncthreads();
  for (int c = wv; c < NC; c += 16) {
    int i = (c << 6) + lane;
    unsigned u = (i < n) ? fkey(score[i]) : 0u;
    bool isgt = (i < n) && (u > uthr);
    bool iseq = (i < n) && (u == uthr);
    unsigned long long mg = __ballot(isgt);
    unsigned long long me = __ballot(iseq);
    if (isgt) {
      int pos = bgt[c] + (int)__popcll(mg & below);
      perm[pos] = i; gatec[pos] = inv_fkey(u); inv[i] = pos;
    } else if (iseq) {
      int er = beq[c] + (int)__popcll(me & below);
      if (er < rem) { int pos = c_gt + er; perm[pos] = i; gatec[pos] = inv_fkey(u); inv[i] = pos; }
    }
  }
}

// ---------------- A1 rows -> CSR + dis1 || yw2-L1 (merged) [R4-verified] ----------------
union RowAU {
  struct { int row[K1N]; int cntw[4]; int wsum; } rc;
  YWShared yw;
};

__global__ __launch_bounds__(256) void k_rowA(const int* __restrict__ perm1,
                                              const int* __restrict__ inv1,
                                              const int* __restrict__ cnt_in,
                                              const int* __restrict__ col_in,
                                              int* __restrict__ csr_n,
                                              int* __restrict__ csr_k,
                                              float* __restrict__ csr_w,
                                              float* __restrict__ dis1,
                                              const float* __restrict__ h0,
                                              const float* __restrict__ Wd1,
                                              float* __restrict__ Ysc) {
  __shared__ RowAU sm;
  int b = blockIdx.x, t = threadIdx.x;
  if (b >= K1N) {
    yw2_body(&sm.yw, b - K1N, h0, nullptr, nullptr, HID, N0, K1N, Wd1, perm1, Ysc);
    return;
  }
  int r = b;
  for (int i = t; i < K1N; i += 256) sm.rc.row[i] = 0;
  if (t == 0) sm.rc.wsum = 0;
  __syncthreads();
  int d = perm1[r];
  int ni = cnt_in[d]; if (ni > CAP) ni = CAP;
  if (t < ni) {
    int s = col_in[d * CAP + t];
    int jj = inv1[s];
    if (jj >= 0) atomicAdd(&sm.rc.row[jj], 2);
  }
  {
    int ta = t >> 3, tb = t & 7;
    for (int a = ta; a < ni; a += 32) {
      int m = col_in[d * CAP + a];
      int nm = cnt_in[m]; if (nm > CAP) nm = CAP;
      for (int bq = tb; bq < nm; bq += 8) {
        int s = col_in[m * CAP + bq];
        if (s != d) {
          int jj = inv1[s];
          if (jj >= 0) atomicAdd(&sm.rc.row[jj], 1);
        }
      }
    }
  }
  __syncthreads();
  int wid = t >> 6, lane = t & 63;
  unsigned long long below = (lane == 0) ? 0ull : (~0ull >> (64 - lane));
  int base = 0, ws = 0;
  int* gk = csr_k + (size_t)r * RCAP;
  float* gw = csr_w + (size_t)r * RCAP;
  for (int c0 = 0; c0 < K1N; c0 += 256) {
    int col = c0 + t;
    int v = (col < K1N) ? sm.rc.row[col] : 0;
    ws += v;
    bool nz = (v != 0);
    unsigned long long m = __ballot(nz);
    if (lane == 0) sm.rc.cntw[wid] = (int)__popcll(m);
    __syncthreads();
    int pref = 0;
#pragma unroll
    for (int w = 0; w < 4; ++w) if (w < wid) pref += sm.rc.cntw[w];
    int pos = base + pref + (int)__popcll(m & below);
    if (nz) { gk[pos] = col; gw[pos] = (float)v; }
    base += sm.rc.cntw[0] + sm.rc.cntw[1] + sm.rc.cntw[2] + sm.rc.cntw[3];
    __syncthreads();
  }
  for (int off = 32; off > 0; off >>= 1) ws += __shfl_down(ws, off);
  if (lane == 0) atomicAdd(&sm.rc.wsum, ws);
  __syncthreads();
  if (t == 0) {
    csr_n[r] = base;
    dis1[r] = 1.0f / sqrtf((float)sm.rc.wsum + 2.0f);
  }
}

// ---------------- CSR spmv + epilogue (+score); col scale STAGED in LDS ----------------
__global__ __launch_bounds__(128) void k_spmv_csr(const int* __restrict__ csr_n,
                                                  const int* __restrict__ csr_k,
                                                  const float* __restrict__ csr_w,
                                                  const float* __restrict__ Yraw,
                                                  const float* __restrict__ dis,
                                                  const float* __restrict__ gate,
                                                  const float* __restrict__ bias,
                                                  const float* __restrict__ p,
                                                  float* __restrict__ H,
                                                  float* __restrict__ score, int act) {
  __shared__ int klist[K1N];
  __shared__ float wlist[K1N];
  __shared__ float slist[K1N];
  __shared__ float red[HID];
  __shared__ float red2[HID];
  int r = blockIdx.x, t = threadIdx.x;
  int nnz = csr_n[r];
  {
    const int* gk = csr_k + (size_t)r * RCAP;
    const float* gw = csr_w + (size_t)r * RCAP;
    for (int i = t; i < nnz; i += 128) {
      int c = gk[i];
      klist[i] = c;
      wlist[i] = gw[i];
      slist[i] = gate ? dis[c] * gate[c] : dis[c];
    }
  }
  __syncthreads();
  float acc = 0.0f;
  int pp = 0;
  for (; pp + 8 <= nnz; pp += 8) {
    float y[8];
#pragma unroll
    for (int j = 0; j < 8; ++j) y[j] = slist[pp + j] * Yraw[(size_t)klist[pp + j] * HID + t];
#pragma unroll
    for (int j = 0; j < 8; ++j) acc += wlist[pp + j] * y[j];
  }
  for (; pp < nnz; ++pp) acc += wlist[pp] * (slist[pp] * Yraw[(size_t)klist[pp] * HID + t]);
  float sr = gate ? dis[r] * gate[r] : dis[r];
  float yr = sr * Yraw[(size_t)r * HID + t];
  float zv = dis[r] * (acc + 2.0f * yr) + bias[t];
  float h = act ? tanhf(zv) : zv;
  H[(size_t)r * HID + t] = h;
  if (p) {
    float pv = p[t];
    red[t] = h * pv;
    red2[t] = pv * pv;
    __syncthreads();
    for (int s = 64; s > 0; s >>= 1) {
      if (t < s) { red[t] += red[t + s]; red2[t] += red2[t + s]; }
      __syncthreads();
    }
    if (t == 0) score[r] = tanhf(red[0] * (1.0f / sqrtf(red2[0])));
  }
}

// ---------------- Ac scatter-build || yw2-L2 (merged) [R4-verified] ----------------
__global__ __launch_bounds__(256) void k_cmpyw(const int* __restrict__ csr_n,
                                               const int* __restrict__ csr_k,
                                               const float* __restrict__ csr_w,
                                               const int* __restrict__ inv2,
                                               short* __restrict__ Ac,
                                               const float* __restrict__ h1,
                                               const float* __restrict__ Wd2,
                                               const int* __restrict__ perm2,
                                               float* __restrict__ Ysc) {
  __shared__ YWShared smy;
  int b = blockIdx.x, t = threadIdx.x;
  if (b >= K1N) {
    yw2_body(&smy, b - K1N, h1, nullptr, nullptr, HID, K1N, K2N, Wd2, perm2, Ysc);
    return;
  }
  short* dst = Ac + (size_t)b * LD2;
  for (int i = t; i < LD2; i += 256) dst[i] = 0;
  __syncthreads();
  int nnz = csr_n[b];
  const int* gk = csr_k + (size_t)b * RCAP;
  const float* gw = csr_w + (size_t)b * RCAP;
  for (int i = t; i < nnz; i += 256) {
    int c = inv2[gk[i]];
    if (c >= 0) dst[c] = (short)gw[i];
  }
}

// ---------------- A2 + dis2 [R5-verified] ----------------
__global__ __launch_bounds__(192) void k_sq2(const short* __restrict__ Ac,
                                             const int* __restrict__ perm2,
                                             const int* __restrict__ csr_n,
                                             const int* __restrict__ csr_k,
                                             const float* __restrict__ csr_w,
                                             float* __restrict__ A2,
                                             float* __restrict__ dis2) {
  __shared__ int klist[K1N];
  __shared__ float wlist[K1N];
  __shared__ float wred[3];
  int a = blockIdx.x, t = threadIdx.x;
  int qa = perm2[a];
  if (qa < 0) qa = 0;
  if (qa >= K1N) qa = K1N - 1;
  const short* acq = Ac + (size_t)qa * LD2;
  int nnz = csr_n[qa];
  {
    const int* gk = csr_k + (size_t)qa * RCAP;
    const float* gw = csr_w + (size_t)qa * RCAP;
    for (int c = t; c < nnz; c += 192) { klist[c] = gk[c]; wlist[c] = gw[c]; }
  }
  __syncthreads();
  int c0 = t * 4;
  float4 acc = make_float4(0.f, 0.f, 0.f, 0.f);
  int p = 0;
  for (; p + 8 <= nnz; p += 8) {
    int kk[8]; float ww[8];
#pragma unroll
    for (int j = 0; j < 8; ++j) { kk[j] = klist[p + j]; ww[j] = wlist[p + j]; }
    short4 v[8];
#pragma unroll
    for (int j = 0; j < 8; ++j) v[j] = *(const short4*)&Ac[(size_t)kk[j] * LD2 + c0];
#pragma unroll
    for (int j = 0; j < 8; ++j) {
      acc.x += ww[j] * (float)v[j].x;
      acc.y += ww[j] * (float)v[j].y;
      acc.z += ww[j] * (float)v[j].z;
      acc.w += ww[j] * (float)v[j].w;
    }
  }
  for (; p < nnz; ++p) {
    int k = klist[p]; float w = wlist[p];
    short4 v = *(const short4*)&Ac[(size_t)k * LD2 + c0];
    acc.x += w * (float)v.x; acc.y += w * (float)v.y;
    acc.z += w * (float)v.z; acc.w += w * (float)v.w;
  }
  float rsum = 0.0f;
  {
    float accv[4] = {acc.x, acc.y, acc.z, acc.w};
    float outv[4];
#pragma unroll
    for (int j = 0; j < 4; ++j) {
      int col = c0 + j;
      float v = 0.0f;
      if (col < K2N && col != a) {
        v = accv[j] + 2.0f * (float)acq[col];
      }
      outv[j] = v;
      rsum += v;
    }
    *(float4*)&A2[(size_t)a * LD2 + c0] = make_float4(outv[0], outv[1], outv[2], outv[3]);
  }
  for (int off = 32; off > 0; off >>= 1) rsum += __shfl_down(rsum, off);
  if ((t & 63) == 0) wred[t >> 6] = rsum;
  __syncthreads();
  if (t == 0) dis2[a] = 1.0f / sqrtf(wred[0] + wred[1] + wred[2] + 2.0f);
}

// ---------------- dense spmv on A2; col scale STAGED in LDS once ----------------
__global__ __launch_bounds__(128) void k_spmv2(const float* __restrict__ A2,
                                               const float* __restrict__ Yraw,
                                               const float* __restrict__ dis2,
                                               const float* __restrict__ gate2,
                                               const float* __restrict__ bias,
                                               float* __restrict__ H) {
  __shared__ float s2[K2N];
  int r = blockIdx.x, t = threadIdx.x;
  for (int c = t; c < K2N; c += 128) s2[c] = dis2[c] * gate2[c];
  __syncthreads();
  const float* arow = A2 + (size_t)r * LD2;
  float acc = 0.0f;
  int c = 0;
  for (; c + 8 <= K2N; c += 8) {
    float w[8], y[8];
#pragma unroll
    for (int j = 0; j < 8; ++j) w[j] = arow[c + j];
#pragma unroll
    for (int j = 0; j < 8; ++j) y[j] = s2[c + j] * Yraw[(size_t)(c + j) * HID + t];
#pragma unroll
    for (int j = 0; j < 8; ++j) acc += w[j] * y[j];
  }
  for (; c < K2N; ++c) acc += arow[c] * (s2[c] * Yraw[(size_t)c * HID + t]);
  float yr = s2[r] * Yraw[(size_t)r * HID + t];
  float zv = dis2[r] * (acc + 2.0f * yr) + bias[t];
  H[(size_t)r * HID + t] = tanhf(zv);
}

// ---------------- up-path spmv + yf FUSED (u1b eliminated) ----------------
// Block i: ii=inv1[i]; if selected, compute CSR row ii of the up-GCN (Ysc is
// dis1-producer-scaled) entirely in registers; then yf reduction for node i.
__global__ __launch_bounds__(128) void k_upyf(const int* __restrict__ inv1,
                                              const int* __restrict__ csr_n,
                                              const int* __restrict__ csr_k,
                                              const float* __restrict__ csr_w,
                                              const float* __restrict__ Ysc,
                                              const float* __restrict__ dis1,
                                              const float* __restrict__ bu0,
                                              const float* __restrict__ h0,
                                              const float* __restrict__ Wup1,
                                              const int* __restrict__ cnt_in,
                                              const int* __restrict__ selfc,
                                              float* __restrict__ Yfsc) {
  __shared__ int klist[K1N];
  __shared__ float wlist[K1N];
  __shared__ float red[3][HID];
  int i = blockIdx.x, t = threadIdx.x;
  int ii = inv1[i];
  float h = 0.0f;
  if (ii >= 0 && ii < K1N) {
    int nnz = csr_n[ii];
    {
      const int* gk = csr_k + (size_t)ii * RCAP;
      const float* gw = csr_w + (size_t)ii * RCAP;
      for (int q = t; q < nnz; q += 128) { klist[q] = gk[q]; wlist[q] = gw[q]; }
    }
    __syncthreads();
    float acc = 0.0f;
    int pp = 0;
    for (; pp + 8 <= nnz; pp += 8) {
      float y[8];
#pragma unroll
      for (int j = 0; j < 8; ++j) y[j] = Ysc[(size_t)klist[pp + j] * HID + t];
#pragma unroll
      for (int j = 0; j < 8; ++j) acc += wlist[pp + j] * y[j];
    }
    for (; pp < nnz; ++pp) acc += wlist[pp] * Ysc[(size_t)klist[pp] * HID + t];
    float zv = dis1[ii] * (acc + 2.0f * Ysc[(size_t)ii * HID + t]) + bu0[t];
    h = tanhf(zv);
  }
  float v = h0[(size_t)i * HID + t] + h;
#pragma unroll
  for (int c = 0; c < 3; ++c) red[c][t] = v * Wup1[t * 3 + c];
  __syncthreads();
  for (int s = 64; s > 0; s >>= 1) {
    if (t < s) { red[0][t] += red[0][t + s]; red[1][t] += red[1][t + s]; red[2][t] += red[2][t + s]; }
    __syncthreads();
  }
  if (t < 3) {
    float d0 = 1.0f / sqrtf((float)(cnt_in[i] + selfc[i] + 2));
    Yfsc[i * 3 + t] = d0 * red[t][0];
  }
}

__global__ void k_final(const float* __restrict__ Yfsc, const int* __restrict__ cnt_in,
                        const int* __restrict__ col_in, const int* __restrict__ selfc,
                        const float* __restrict__ bup1, const float* __restrict__ z,
                        float* __restrict__ out) {
  int idx = blockIdx.x * blockDim.x + threadIdx.x;
  if (idx >= N0 * 3) return;
  int d = idx / 3, c = idx - d * 3;
  int cntu = cnt_in[d];
  int cnt = cntu > CAP ? CAP : cntu;
  float acc = (2.0f + (float)selfc[d]) * Yfsc[d * 3 + c];
  int e = 0;
  for (; e + 8 <= cnt; e += 8) {
    float y[8];
#pragma unroll
    for (int j = 0; j < 8; ++j) y[j] = Yfsc[col_in[d * CAP + e + j] * 3 + c];
#pragma unroll
    for (int j = 0; j < 8; ++j) acc += y[j];
  }
  for (; e < cnt; ++e) acc += Yfsc[col_in[d * CAP + e] * 3 + c];
  float d0 = 1.0f / sqrtf((float)(cntu + selfc[d] + 2));
  out[idx] = d0 * acc + bup1[c] + 0.1f * z[idx];
}

extern "C" void kernel_launch(void* const* d_in, const int* in_sizes, int n_in,
                              void* d_out, int out_size, void* d_ws, size_t ws_size,
                              hipStream_t stream) {
  const float* x   = (const float*)d_in[0];
  const float* z   = (const float*)d_in[1];
  const float* Wd0 = (const float*)d_in[2];
  const float* bd0 = (const float*)d_in[3];
  const float* Wd1 = (const float*)d_in[4];
  const float* bd1 = (const float*)d_in[5];
  const float* Wd2 = (const float*)d_in[6];
  const float* bd2 = (const float*)d_in[7];
  const float* p1  = (const float*)d_in[8];
  const float* p2  = (const float*)d_in[9];
  const float* Wu0 = (const float*)d_in[10];
  const float* bu0 = (const float*)d_in[11];
  const float* Wu1 = (const float*)d_in[12];
  const float* bu1 = (const float*)d_in[13];
  const int*   ei  = (const int*)d_in[14];

  if (ws_size < F_END * sizeof(float)) return;

  float* W     = (float*)d_ws;
  short* Ac    = (short*)(W + F_SCR);
  float* A2    = W + F_A2;
  float* Ysc   = W + F_YSC;
  float* h0    = W + F_H0;
  float* h1    = W + F_H1;
  float* h2    = W + F_H2;
  float* Yfsc  = W + F_YF;
  float* score = W + F_SCORE;
  float* gate1 = W + F_GATE1;
  float* gate2 = W + F_GATE2;
  float* dis1  = W + F_DIS1;
  float* dis2  = W + F_DIS2;
  int* perm1   = (int*)(W + F_PERM1);
  int* perm2   = (int*)(W + F_PERM2);
  int* inv1    = (int*)(W + F_INV1);
  int* inv2    = (int*)(W + F_INV2);
  int* cnt_in  = (int*)(W + F_CNTI);
  int* selfc   = (int*)(W + F_SELF);
  int* col_in  = (int*)(W + F_CI);
  int* csr_n   = (int*)(W + F_CSRN);
  int* csr_k   = (int*)(W + F_CSRK);
  float* csr_w = W + F_CSRW;
  float* out   = (float*)d_out;

  // 1. fills
  k_init<<<128, 256, 0, stream>>>(gate1, perm1, inv1, cnt_in, out + N0 * 3);
  // 2. edge lists || level-0 YW (unscaled)
  k_cntyw<<<NBC + NBY0, 256, 0, stream>>>(ei, cnt_in, selfc, col_in, x, Wd0, Ysc);
  // 3. level-0 GCN + pool-1 score (col scale at dst, R4-verified)
  k_gcn_sparse<<<N0, HID, 0, stream>>>(Ysc, cnt_in, col_in, selfc, bd0, p1, h0, score);
  // 4. top-K #1
  k_topk<<<1, TKT, 0, stream>>>(score, N0, K1N, perm1, gate1, inv1);
  // 5. A1 CSR + dis1 || level-1 YW (unscaled)
  k_rowA<<<K1N + NBY1, 256, 0, stream>>>(perm1, inv1, cnt_in, col_in,
                                         csr_n, csr_k, csr_w, dis1, h0, Wd1, Ysc);
  // 6. level-1 spmv + pool-2 score (col scale LDS-staged)
  k_spmv_csr<<<K1N, 128, 0, stream>>>(csr_n, csr_k, csr_w, Ysc, dis1, gate1, bd1, p2,
                                      h1, score, 1);
  // 7. top-K #2
  k_topk<<<1, TKT, 0, stream>>>(score, K1N, K2N, perm2, gate2, inv2);
  // 8. Ac scatter-build || level-2 YW (unscaled)
  k_cmpyw<<<K1N + NBY2, 256, 0, stream>>>(csr_n, csr_k, csr_w, inv2, Ac, h1, Wd2, perm2, Ysc);
  // 9. A2 + dis2
  k_sq2<<<K2N, 192, 0, stream>>>(Ac, perm2, csr_n, csr_k, csr_w, A2, dis2);
  // 10. level-2 dense spmv (col scale LDS-staged once)
  k_spmv2<<<K2N, 128, 0, stream>>>(A2, Ysc, dis2, gate2, bd2, h2);
  // 11. up-path YW (producer-scaled by dis1; available since stage 5)
  k_yw2<<<NBY1, 256, 0, stream>>>(h1, h2, inv2, HID, K1N, K1N, Wu0,
                                  nullptr, nullptr, dis1, Ysc);
  // 12. up-path spmv + yf fused (u1b eliminated)
  k_upyf<<<N0, 128, 0, stream>>>(inv1, csr_n, csr_k, csr_w, Ysc, dis1, bu0,
                                 h0, Wu1, cnt_in, selfc, Yfsc);
  // 13. final
  k_final<<<(N0 * 3 + 255) / 256, 256, 0, stream>>>(Yfsc, cnt_in, col_in, selfc, bu1, z, out);
}